// Round 5
// baseline (409.366 us; speedup 1.0000x reference)
//
#include <hip/hip_runtime.h>

#define IN_DIM   128
#define HC       256   // HEADS*OUT_DIM
#define OUT_DIM  64
#define HEADS    4
#define NEG_SLOPE 0.2f
#define LN_EPS   1e-5f

typedef short bf16x8 __attribute__((ext_vector_type(8)));
typedef float f32x4  __attribute__((ext_vector_type(4)));

__device__ __forceinline__ float lrelu(float a){ return a > 0.f ? a : NEG_SLOPE * a; }

__device__ __forceinline__ unsigned short f2bf(float f){
  unsigned u = __float_as_uint(f);
  u = u + 0x7fffu + ((u >> 16) & 1u);   // round-to-nearest-even
  return (unsigned short)(u >> 16);
}
__device__ __forceinline__ unsigned pk2(float a, float b){
  return (unsigned)f2bf(a) | ((unsigned)f2bf(b) << 16);
}
__device__ __forceinline__ float bflo(unsigned u){ return __uint_as_float(u << 16); }
__device__ __forceinline__ float bfhi(unsigned u){ return __uint_as_float(u & 0xffff0000u); }

__device__ __forceinline__ float wsum(float v){
  #pragma unroll
  for (int o = 32; o; o >>= 1) v += __shfl_xor(v, o);
  return v;
}

// Per-wave int32/int64 layout detection: int64 node ids < 2^31 have zero odd
// 32-bit words; int32 layout would need 32 random node ids == 0 to fool this.
__device__ __forceinline__ bool detect32(const int* ei){
  int ln = threadIdx.x & 63;
  unsigned probe = (ln < 32) ? (unsigned)ei[2*ln + 1] : 0u;
  return __ballot(probe != 0) != 0ull;
}

// Wt[n][k] = bf16(W[k][n]) (MFMA B-frag friendly) + grid-stride zero of deg.
__global__ void k_prep(const float* __restrict__ W, unsigned short* __restrict__ Wt,
                       int* deg, int N){
  int n = blockIdx.x;          // 0..255
  int k = threadIdx.x;         // 0..127
  Wt[n*IN_DIM + k] = f2bf(W[k*HC + n]);
  for (int i = blockIdx.x*blockDim.x + threadIdx.x; i < N; i += gridDim.x*blockDim.x)
    deg[i] = 0;
}

// MFMA GEMM: xl_t = bf16(x @ W) head-interleaved [node][ch*4+head],
// plus fp32 logits a_src/a_dst from the fp32 accumulators.
// Block: 16 nodes x 256 cols; 4 waves; wave w owns head w (64 cols = 4 N-tiles).
__global__ __launch_bounds__(256) void k_gemm_mfma(
    const float* __restrict__ x, const unsigned short* __restrict__ Wt,
    const float* __restrict__ att_s, const float* __restrict__ att_d,
    unsigned short* __restrict__ xl_t, float* __restrict__ a_src,
    float* __restrict__ a_dst, int N)
{
  __shared__ unsigned short sxa[16*IN_DIM];   // 4KB bf16 x-tile, XOR-swizzled
  __shared__ unsigned short sxl[16*HC];       // 8KB output staging
  int t = threadIdx.x;
  int nb = blockIdx.x * 16;

  // ---- stage A tile (16 nodes x 128 k) as bf16, swizzled ----
  {
    int row = t >> 4, seg = t & 15;
    const float* xr = x + (size_t)(nb + row)*IN_DIM + seg*8;
    float4 f0 = *(const float4*)xr;
    float4 f1 = *(const float4*)(xr + 4);
    uint4 pk;
    pk.x = pk2(f0.x, f0.y); pk.y = pk2(f0.z, f0.w);
    pk.z = pk2(f1.x, f1.y); pk.w = pk2(f1.z, f1.w);
    int byte = (row*256 + seg*16) ^ ((row & 7) << 4);
    *(uint4*)((char*)sxa + byte) = pk;
  }
  __syncthreads();

  int w = t >> 6, l = t & 63;

  // ---- A fragments: lane l holds A[row=l&15][k = ks*32 + (l>>4)*8 .. +8] ----
  bf16x8 afr[4];
  #pragma unroll
  for (int ks = 0; ks < 4; ++ks){
    int row = l & 15;
    int byte = (row*256 + ks*64 + ((l >> 4) << 4)) ^ ((row & 7) << 4);
    afr[ks] = *(const bf16x8*)((const char*)sxa + byte);
  }

  f32x4 acc[4] = {{0,0,0,0},{0,0,0,0},{0,0,0,0},{0,0,0,0}};
  #pragma unroll
  for (int nt = 0; nt < 4; ++nt){
    int col = w*64 + nt*16 + (l & 15);
    #pragma unroll
    for (int ks = 0; ks < 4; ++ks){
      const unsigned short* bp = Wt + (size_t)col*IN_DIM + ks*32 + ((l >> 4) << 3);
      bf16x8 bfr = *(const bf16x8*)bp;
      acc[nt] = __builtin_amdgcn_mfma_f32_16x16x32_bf16(afr[ks], bfr, acc[nt], 0, 0, 0);
    }
  }

  // ---- logits from fp32 accumulators ----
  float attS[4], attD[4];
  #pragma unroll
  for (int nt = 0; nt < 4; ++nt){
    attS[nt] = att_s[w*64 + nt*16 + (l & 15)];
    attD[nt] = att_d[w*64 + nt*16 + (l & 15)];
  }
  #pragma unroll
  for (int r = 0; r < 4; ++r){
    float ps = 0.f, pd = 0.f;
    #pragma unroll
    for (int nt = 0; nt < 4; ++nt){
      ps = fmaf(acc[nt][r], attS[nt], ps);
      pd = fmaf(acc[nt][r], attD[nt], pd);
    }
    #pragma unroll
    for (int o = 8; o; o >>= 1){ ps += __shfl_xor(ps, o); pd += __shfl_xor(pd, o); }
    if ((l & 15) == 0){
      int node = nb + (l >> 4)*4 + r;
      a_src[node*4 + w] = ps;
      a_dst[node*4 + w] = pd;
    }
  }

  // ---- stage bf16 tile in xl_t layout, then coalesced copy-out ----
  #pragma unroll
  for (int nt = 0; nt < 4; ++nt){
    int ch = nt*16 + (l & 15);
    #pragma unroll
    for (int r = 0; r < 4; ++r){
      int row = (l >> 4)*4 + r;
      sxl[row*HC + ch*4 + w] = f2bf(acc[nt][r]);
    }
  }
  __syncthreads();
  const uint4* s4 = (const uint4*)sxl;
  uint4* g4 = (uint4*)(xl_t + (size_t)nb*HC);
  #pragma unroll
  for (int c = t; c < 512; c += 256) g4[c] = s4[c];
}

__global__ void k_hist(const int* ei, int* deg, int E){
  bool i32 = detect32(ei);
  int i = blockIdx.x*blockDim.x + threadIdx.x;
  if (i >= E) return;
  int d = i32 ? ei[E + i] : (int)((const long long*)ei)[(size_t)E + i];
  atomicAdd(&deg[d], 1);
}

__global__ __launch_bounds__(256) void k_scan1(const int* __restrict__ deg,
    int* rowstart, int* partial, int N){
  __shared__ int sh[256];
  int tid = threadIdx.x;
  int base = blockIdx.x*1024 + tid*4;
  int d[4]; int ts = 0;
  #pragma unroll
  for (int k = 0; k < 4; ++k){
    d[k] = (base+k < N) ? deg[base+k] : 0;
    ts += d[k];
  }
  sh[tid] = ts; __syncthreads();
  #pragma unroll
  for (int off = 1; off < 256; off <<= 1){
    int t = (tid >= off) ? sh[tid-off] : 0;
    __syncthreads();
    sh[tid] += t;
    __syncthreads();
  }
  int run = sh[tid] - ts;
  #pragma unroll
  for (int k = 0; k < 4; ++k){
    if (base+k < N) rowstart[base+k] = run;
    run += d[k];
  }
  if (tid == 255) partial[blockIdx.x] = sh[255];
}

__global__ __launch_bounds__(1024) void k_scan2(int* partial, int nb){
  __shared__ int sh[1024];
  int tid = threadIdx.x;
  int v = (tid < nb) ? partial[tid] : 0;
  sh[tid] = v; __syncthreads();
  #pragma unroll
  for (int off = 1; off < 1024; off <<= 1){
    int t = (tid >= off) ? sh[tid-off] : 0;
    __syncthreads();
    sh[tid] += t;
    __syncthreads();
  }
  if (tid < nb) partial[tid] = sh[tid] - v;  // exclusive
}

__global__ void k_scan3(int* rowstart, const int* __restrict__ partial,
                        int* cursor, int N, int E){
  int i = blockIdx.x*blockDim.x + threadIdx.x;
  if (i < N){
    int v = rowstart[i] + partial[i >> 10];
    rowstart[i] = v;
    cursor[i] = v;
  }
  if (i == N) rowstart[N] = E;
}

__global__ void k_fill(const int* ei, int* cursor, int* csr, int E){
  bool i32 = detect32(ei);
  int i = blockIdx.x*blockDim.x + threadIdx.x;
  if (i >= E) return;
  int s, d;
  if (i32){ s = ei[i]; d = ei[E + i]; }
  else {
    s = (int)((const long long*)ei)[i];
    d = (int)((const long long*)ei)[(size_t)E + i];
  }
  int pos = atomicAdd(&cursor[d], 1);
  csr[pos] = s;
}

// One wave per destination node. Direct softmax (no max-subtraction: logits
// are O(1) by construction, exp cannot overflow in fp32; softmax is
// shift-invariant so the result matches the reference).
// Phase A (lane=edge): weights -> LDS. Phase B (lane=channel): serial PV
// with wave-uniform ds_read_b128 weight broadcast + scalar-base gathers.
__global__ __launch_bounds__(256) void k_node(
    const int* __restrict__ rowstart, const int* __restrict__ csr,
    const float4* __restrict__ a_src4, const float4* __restrict__ a_dst4,
    const unsigned short* __restrict__ xl_t,
    const float* __restrict__ bias, const float* __restrict__ gamma,
    const float* __restrict__ beta, float* __restrict__ out, int N)
{
  __shared__ float4 wlds[4][64];
  int wv = threadIdx.x >> 6, ln = threadIdx.x & 63;
  int node = blockIdx.x*4 + wv;
  if (node >= N) return;

  int start = rowstart[node], end = rowstart[node+1];
  float4 ad = a_dst4[node];
  float4 asl = a_src4[node];

  // self-loop
  float es0 = __expf(lrelu(asl.x + ad.x));
  float es1 = __expf(lrelu(asl.y + ad.y));
  float es2 = __expf(lrelu(asl.z + ad.z));
  float es3 = __expf(lrelu(asl.w + ad.w));
  uint2 xs = *(const uint2*)(xl_t + (size_t)node*HC + ln*4);
  float acc0 = es0 * bflo(xs.x);
  float acc1 = es1 * bfhi(xs.x);
  float acc2 = es2 * bflo(xs.y);
  float acc3 = es3 * bfhi(xs.y);
  float lp0 = 0.f, lp1 = 0.f, lp2 = 0.f, lp3 = 0.f;  // per-lane denom partials

  for (int t = start; t < end; t += 64){
    int nt = end - t; if (nt > 64) nt = 64;
    int sid = 0;
    float e0 = 0.f, e1 = 0.f, e2 = 0.f, e3 = 0.f;
    if (ln < nt){
      sid = csr[t + ln];
      float4 as4 = a_src4[sid];
      e0 = __expf(lrelu(as4.x + ad.x));
      e1 = __expf(lrelu(as4.y + ad.y));
      e2 = __expf(lrelu(as4.z + ad.z));
      e3 = __expf(lrelu(as4.w + ad.w));
      lp0 += e0; lp1 += e1; lp2 += e2; lp3 += e3;
    }
    wlds[wv][ln] = make_float4(e0, e1, e2, e3);

    #pragma unroll 8
    for (int j = 0; j < nt; ++j){
      int sj = __builtin_amdgcn_readlane(sid, j);     // scalar -> SGPR base
      float4 wj = wlds[wv][j];                        // uniform addr broadcast
      uint2 xv = *(const uint2*)(xl_t + (size_t)sj*HC + ln*4);
      acc0 = fmaf(wj.x, bflo(xv.x), acc0);
      acc1 = fmaf(wj.y, bfhi(xv.x), acc1);
      acc2 = fmaf(wj.z, bflo(xv.y), acc2);
      acc3 = fmaf(wj.w, bfhi(xv.y), acc3);
    }
  }

  float l0 = es0 + wsum(lp0);
  float l1 = es1 + wsum(lp1);
  float l2 = es2 + wsum(lp2);
  float l3 = es3 + wsum(lp3);

  float o = 0.25f*(acc0/l0 + acc1/l1 + acc2/l2 + acc3/l3) + bias[ln];
  float s  = wsum(o);
  float sq = wsum(o*o);
  float mu = s * (1.f/OUT_DIM);
  float var = sq * (1.f/OUT_DIM) - mu*mu;
  float rs = rsqrtf(var + LN_EPS);
  out[(size_t)node*OUT_DIM + ln] = (o - mu) * rs * gamma[ln] + beta[ln];
}

extern "C" void kernel_launch(void* const* d_in, const int* in_sizes, int n_in,
                              void* d_out, int out_size, void* d_ws, size_t ws_size,
                              hipStream_t stream)
{
  const float* x     = (const float*)d_in[0];
  const int*   ei    = (const int*)d_in[1];
  const float* W     = (const float*)d_in[2];
  const float* att_s = (const float*)d_in[3];
  const float* att_d = (const float*)d_in[4];
  const float* bias  = (const float*)d_in[5];
  const float* gamma = (const float*)d_in[6];
  const float* beta  = (const float*)d_in[7];
  float* out = (float*)d_out;

  int N = in_sizes[0] / IN_DIM;
  int E = in_sizes[1] / 2;

  char* ws = (char*)d_ws;
  unsigned short* xl_t = (unsigned short*)ws;   ws += (size_t)N*HC*sizeof(unsigned short);
  float* a_src = (float*)ws;                    ws += (size_t)N*HEADS*sizeof(float);
  float* a_dst = (float*)ws;                    ws += (size_t)N*HEADS*sizeof(float);
  int* deg      = (int*)ws;                     ws += (size_t)N*sizeof(int);
  int* cursor   = (int*)ws;                     ws += (size_t)N*sizeof(int);
  int* rowstart = (int*)ws;                     ws += ((size_t)N+1)*sizeof(int);
  int* partial  = (int*)ws;                     ws += 1024*sizeof(int);
  int* csr      = (int*)ws;                     ws += (size_t)E*sizeof(int);
  unsigned short* Wt = (unsigned short*)ws;     ws += (size_t)HC*IN_DIM*sizeof(unsigned short);

  int nb1 = (N + 1023) / 1024;

  k_prep  <<<HC, IN_DIM, 0, stream>>>(W, Wt, deg, N);
  k_gemm_mfma<<<(N + 15)/16, 256, 0, stream>>>(x, Wt, att_s, att_d, xl_t, a_src, a_dst, N);
  k_hist  <<<(E + 255)/256, 256, 0, stream>>>(ei, deg, E);
  k_scan1 <<<nb1, 256, 0, stream>>>(deg, rowstart, partial, N);
  k_scan2 <<<1, 1024, 0, stream>>>(partial, nb1);
  k_scan3 <<<(N + 256)/256, 256, 0, stream>>>(rowstart, partial, cursor, N, E);
  k_fill  <<<(E + 255)/256, 256, 0, stream>>>(ei, cursor, csr, E);
  k_node  <<<(N + 3)/4, 256, 0, stream>>>(rowstart, csr,
            (const float4*)a_src, (const float4*)a_dst, xl_t,
            bias, gamma, beta, out, N);
}

// Round 6
// 360.634 us; speedup vs baseline: 1.1351x; 1.1351x over previous
//
#include <hip/hip_runtime.h>
#include <hip/hip_fp16.h>

#define IN_DIM   128
#define HC       256   // HEADS*OUT_DIM
#define OUT_DIM  64
#define HEADS    4
#define NEG_SLOPE 0.2f
#define LN_EPS   1e-5f

typedef short bf16x8 __attribute__((ext_vector_type(8)));
typedef float f32x4  __attribute__((ext_vector_type(4)));

__device__ __forceinline__ float lrelu(float a){ return a > 0.f ? a : NEG_SLOPE * a; }

__device__ __forceinline__ unsigned short f2bf(float f){
  unsigned u = __float_as_uint(f);
  u = u + 0x7fffu + ((u >> 16) & 1u);   // round-to-nearest-even
  return (unsigned short)(u >> 16);
}
__device__ __forceinline__ unsigned pk2(float a, float b){
  return (unsigned)f2bf(a) | ((unsigned)f2bf(b) << 16);
}
__device__ __forceinline__ __half2 u2h(unsigned u){ return *(__half2*)&u; }
__device__ __forceinline__ unsigned h2u(__half2 h){ return *(unsigned*)&h; }

__device__ __forceinline__ float wsum(float v){
  #pragma unroll
  for (int o = 32; o; o >>= 1) v += __shfl_xor(v, o);
  return v;
}

// Per-wave int32/int64 layout detection: int64 node ids < 2^31 have zero odd
// 32-bit words; int32 layout would need 32 random node ids == 0 to fool this.
__device__ __forceinline__ bool detect32(const int* ei){
  int ln = threadIdx.x & 63;
  unsigned probe = (ln < 32) ? (unsigned)ei[2*ln + 1] : 0u;
  return __ballot(probe != 0) != 0ull;
}

// Wt[n][k] = bf16(W[k][n]) (MFMA B-frag friendly) + grid-stride zero of deg.
__global__ void k_prep(const float* __restrict__ W, unsigned short* __restrict__ Wt,
                       int* deg, int N){
  int n = blockIdx.x;          // 0..255
  int k = threadIdx.x;         // 0..127
  Wt[n*IN_DIM + k] = f2bf(W[k*HC + n]);
  for (int i = blockIdx.x*blockDim.x + threadIdx.x; i < N; i += gridDim.x*blockDim.x)
    deg[i] = 0;
}

// MFMA GEMM: xl_t = fp16(x @ W) head-interleaved [node][ch*4+head],
// plus fp32 logits a_src/a_dst from the fp32 accumulators.
// Block: 64 nodes x 256 cols; 4 waves; wave w owns head w. B fragments are
// loaded ONCE per block into registers and reused across 4 node sub-tiles
// (cuts Wt re-read traffic 4x vs 16-node blocks).
__global__ __launch_bounds__(256) void k_gemm_mfma(
    const float* __restrict__ x, const unsigned short* __restrict__ Wt,
    const float* __restrict__ att_s, const float* __restrict__ att_d,
    __half* __restrict__ xl_t, float* __restrict__ a_src,
    float* __restrict__ a_dst, int N)
{
  __shared__ unsigned short sxa[64*IN_DIM];   // 16KB bf16 x-tile, XOR-swizzled
  __shared__ unsigned short sxl[64*HC];       // 32KB fp16 output staging
  int t = threadIdx.x;
  int nb = blockIdx.x * 64;

  // ---- stage A tile (64 nodes x 128 k) as bf16, swizzled ----
  #pragma unroll
  for (int it = 0; it < 4; ++it){
    int idx = it*256 + t;
    int row = idx >> 4, seg = idx & 15;
    uint4 pk = make_uint4(0,0,0,0);
    if (nb + row < N){
      const float* xr = x + (size_t)(nb + row)*IN_DIM + seg*8;
      float4 f0 = *(const float4*)xr;
      float4 f1 = *(const float4*)(xr + 4);
      pk.x = pk2(f0.x, f0.y); pk.y = pk2(f0.z, f0.w);
      pk.z = pk2(f1.x, f1.y); pk.w = pk2(f1.z, f1.w);
    }
    int byte = (row*256 + seg*16) ^ ((row & 7) << 4);
    *(uint4*)((char*)sxa + byte) = pk;
  }
  __syncthreads();

  int w = t >> 6, l = t & 63;

  // ---- B fragments: load once, reuse for all 4 sub-tiles ----
  bf16x8 bfr[4][4];
  #pragma unroll
  for (int nt = 0; nt < 4; ++nt){
    int col = w*64 + nt*16 + (l & 15);
    #pragma unroll
    for (int ks = 0; ks < 4; ++ks)
      bfr[nt][ks] = *(const bf16x8*)(Wt + (size_t)col*IN_DIM + ks*32 + ((l >> 4) << 3));
  }
  float attS[4], attD[4];
  #pragma unroll
  for (int nt = 0; nt < 4; ++nt){
    attS[nt] = att_s[w*64 + nt*16 + (l & 15)];
    attD[nt] = att_d[w*64 + nt*16 + (l & 15)];
  }

  #pragma unroll
  for (int sub = 0; sub < 4; ++sub){
    // A fragments for rows sub*16 .. sub*16+15
    bf16x8 afr[4];
    #pragma unroll
    for (int ks = 0; ks < 4; ++ks){
      int row = sub*16 + (l & 15);
      int byte = (row*256 + ks*64 + ((l >> 4) << 4)) ^ ((row & 7) << 4);
      afr[ks] = *(const bf16x8*)((const char*)sxa + byte);
    }
    f32x4 acc[4] = {{0,0,0,0},{0,0,0,0},{0,0,0,0},{0,0,0,0}};
    #pragma unroll
    for (int nt = 0; nt < 4; ++nt)
      #pragma unroll
      for (int ks = 0; ks < 4; ++ks)
        acc[nt] = __builtin_amdgcn_mfma_f32_16x16x32_bf16(afr[ks], bfr[nt][ks], acc[nt], 0, 0, 0);

    // logits
    #pragma unroll
    for (int r = 0; r < 4; ++r){
      float ps = 0.f, pd = 0.f;
      #pragma unroll
      for (int nt = 0; nt < 4; ++nt){
        ps = fmaf(acc[nt][r], attS[nt], ps);
        pd = fmaf(acc[nt][r], attD[nt], pd);
      }
      #pragma unroll
      for (int o = 8; o; o >>= 1){ ps += __shfl_xor(ps, o); pd += __shfl_xor(pd, o); }
      int node = nb + sub*16 + (l >> 4)*4 + r;
      if ((l & 15) == 0 && node < N){
        a_src[node*4 + w] = ps;
        a_dst[node*4 + w] = pd;
      }
    }

    // stage fp16 tile in xl_t layout
    #pragma unroll
    for (int nt = 0; nt < 4; ++nt){
      int ch = nt*16 + (l & 15);
      #pragma unroll
      for (int r = 0; r < 4; ++r){
        int row = sub*16 + (l >> 4)*4 + r;
        sxl[row*HC + ch*4 + w] = __half_as_ushort(__float2half(acc[nt][r]));
      }
    }
  }
  __syncthreads();
  const uint4* s4 = (const uint4*)sxl;
  uint4* g4 = (uint4*)(xl_t + (size_t)nb*HC);
  for (int c = t; c < 2048; c += 256){
    int row = c >> 5;
    if (nb + row < N) g4[c] = s4[c];
  }
}

__global__ void k_hist(const int* ei, int* deg, int E){
  bool i32 = detect32(ei);
  int i = blockIdx.x*blockDim.x + threadIdx.x;
  if (i >= E) return;
  int d = i32 ? ei[E + i] : (int)((const long long*)ei)[(size_t)E + i];
  atomicAdd(&deg[d], 1);
}

__global__ __launch_bounds__(256) void k_scan1(const int* __restrict__ deg,
    int* rowstart, int* partial, int N){
  __shared__ int sh[256];
  int tid = threadIdx.x;
  int base = blockIdx.x*1024 + tid*4;
  int d[4]; int ts = 0;
  #pragma unroll
  for (int k = 0; k < 4; ++k){
    d[k] = (base+k < N) ? deg[base+k] : 0;
    ts += d[k];
  }
  sh[tid] = ts; __syncthreads();
  #pragma unroll
  for (int off = 1; off < 256; off <<= 1){
    int t = (tid >= off) ? sh[tid-off] : 0;
    __syncthreads();
    sh[tid] += t;
    __syncthreads();
  }
  int run = sh[tid] - ts;
  #pragma unroll
  for (int k = 0; k < 4; ++k){
    if (base+k < N) rowstart[base+k] = run;
    run += d[k];
  }
  if (tid == 255) partial[blockIdx.x] = sh[255];
}

__global__ __launch_bounds__(1024) void k_scan2(int* partial, int nb){
  __shared__ int sh[1024];
  int tid = threadIdx.x;
  int v = (tid < nb) ? partial[tid] : 0;
  sh[tid] = v; __syncthreads();
  #pragma unroll
  for (int off = 1; off < 1024; off <<= 1){
    int t = (tid >= off) ? sh[tid-off] : 0;
    __syncthreads();
    sh[tid] += t;
    __syncthreads();
  }
  if (tid < nb) partial[tid] = sh[tid] - v;  // exclusive
}

__global__ void k_scan3(int* rowstart, const int* __restrict__ partial,
                        int* cursor, int N, int E){
  int i = blockIdx.x*blockDim.x + threadIdx.x;
  if (i < N){
    int v = rowstart[i] + partial[i >> 10];
    rowstart[i] = v;
    cursor[i] = v;
  }
  if (i == N) rowstart[N] = E;
}

__global__ void k_fill(const int* ei, int* cursor, int* csr, int E){
  bool i32 = detect32(ei);
  int i = blockIdx.x*blockDim.x + threadIdx.x;
  if (i >= E) return;
  int s, d;
  if (i32){ s = ei[i]; d = ei[E + i]; }
  else {
    s = (int)((const long long*)ei)[i];
    d = (int)((const long long*)ei)[(size_t)E + i];
  }
  int pos = atomicAdd(&cursor[d], 1);
  csr[pos] = s;
}

// One wave per destination node. Direct softmax (logits O(1), exp safe in f32,
// shift-invariance makes it exact). Phase A (lane=edge): exp weights packed to
// fp16 pairs in LDS. Phase B: 4 groups of 16 lanes, each group one edge; lane
// covers 32B (16 interleaved fp16 elems = 4ch x 4heads); 8 v_pk_fma_f16 per
// 4 edges. Group-combine + LN in epilogue.
__global__ __launch_bounds__(256) void k_node(
    const int* __restrict__ rowstart, const int* __restrict__ csr,
    const float4* __restrict__ a_src4, const float4* __restrict__ a_dst4,
    const __half* __restrict__ xl_t,
    const float* __restrict__ bias, const float* __restrict__ gamma,
    const float* __restrict__ beta, float* __restrict__ out, int N)
{
  __shared__ uint2 wlds[4][64];
  __shared__ int   slds[4][64];
  int wv = threadIdx.x >> 6, ln = threadIdx.x & 63;
  int node = blockIdx.x*4 + wv;
  if (node >= N) return;
  int g = ln >> 4, i = ln & 15;

  int start = rowstart[node], end = rowstart[node+1];
  float4 ad = a_dst4[node];
  float4 asl = a_src4[node];

  float es0 = __expf(lrelu(asl.x + ad.x));
  float es1 = __expf(lrelu(asl.y + ad.y));
  float es2 = __expf(lrelu(asl.z + ad.z));
  float es3 = __expf(lrelu(asl.w + ad.w));

  __half2 acc[8];
  #pragma unroll
  for (int m = 0; m < 8; ++m) acc[m] = __float2half2_rn(0.f);
  float lp0 = 0.f, lp1 = 0.f, lp2 = 0.f, lp3 = 0.f;

  for (int t = start; t < end; t += 64){
    int nt = end - t; if (nt > 64) nt = 64;
    int sid = 0;
    float e0 = 0.f, e1 = 0.f, e2 = 0.f, e3 = 0.f;
    if (ln < nt){
      sid = csr[t + ln];
      float4 as4 = a_src4[sid];
      e0 = __expf(lrelu(as4.x + ad.x));
      e1 = __expf(lrelu(as4.y + ad.y));
      e2 = __expf(lrelu(as4.z + ad.z));
      e3 = __expf(lrelu(as4.w + ad.w));
      lp0 += e0; lp1 += e1; lp2 += e2; lp3 += e3;
    }
    wlds[wv][ln] = make_uint2(h2u(__floats2half2_rn(e0, e1)),
                              h2u(__floats2half2_rn(e2, e3)));
    slds[wv][ln] = sid;

    int nwin = (nt + 3) >> 2;
    for (int j = 0; j < nwin; ++j){
      int e = j*4 + g;
      uint2 wpk = wlds[wv][e];
      int sj = slds[wv][e];
      __half2 w01 = u2h(wpk.x), w23 = u2h(wpk.y);
      const uint4* p = (const uint4*)((const char*)xl_t + ((size_t)sj*512 + (i << 5)));
      uint4 xa = p[0], xb = p[1];
      acc[0] = __hfma2(w01, u2h(xa.x), acc[0]);
      acc[1] = __hfma2(w23, u2h(xa.y), acc[1]);
      acc[2] = __hfma2(w01, u2h(xa.z), acc[2]);
      acc[3] = __hfma2(w23, u2h(xa.w), acc[3]);
      acc[4] = __hfma2(w01, u2h(xb.x), acc[4]);
      acc[5] = __hfma2(w23, u2h(xb.y), acc[5]);
      acc[6] = __hfma2(w01, u2h(xb.z), acc[6]);
      acc[7] = __hfma2(w23, u2h(xb.w), acc[7]);
    }
  }

  // combine the 4 edge-groups (lanes i, i+16, i+32, i+48 hold same channels)
  #pragma unroll
  for (int m = 0; m < 8; ++m){
    acc[m] = __hadd2(acc[m], u2h(__shfl_xor(h2u(acc[m]), 16)));
    acc[m] = __hadd2(acc[m], u2h(__shfl_xor(h2u(acc[m]), 32)));
  }

  // self-loop (uniform across replicas)
  {
    __half2 s01 = __floats2half2_rn(es0, es1);
    __half2 s23 = __floats2half2_rn(es2, es3);
    const uint4* p = (const uint4*)((const char*)xl_t + ((size_t)node*512 + (i << 5)));
    uint4 xa = p[0], xb = p[1];
    acc[0] = __hfma2(s01, u2h(xa.x), acc[0]);
    acc[1] = __hfma2(s23, u2h(xa.y), acc[1]);
    acc[2] = __hfma2(s01, u2h(xa.z), acc[2]);
    acc[3] = __hfma2(s23, u2h(xa.w), acc[3]);
    acc[4] = __hfma2(s01, u2h(xb.x), acc[4]);
    acc[5] = __hfma2(s23, u2h(xb.y), acc[5]);
    acc[6] = __hfma2(s01, u2h(xb.z), acc[6]);
    acc[7] = __hfma2(s23, u2h(xb.w), acc[7]);
  }

  // denominators: packed fp16 wave reduce of per-lane partials + self term
  __half2 lp01 = __floats2half2_rn(lp0, lp1);
  __half2 lp23 = __floats2half2_rn(lp2, lp3);
  #pragma unroll
  for (int o = 32; o; o >>= 1){
    lp01 = __hadd2(lp01, u2h(__shfl_xor(h2u(lp01), o)));
    lp23 = __hadd2(lp23, u2h(__shfl_xor(h2u(lp23), o)));
  }
  float r0 = __builtin_amdgcn_rcpf(__low2float(lp01) + es0);
  float r1 = __builtin_amdgcn_rcpf(__high2float(lp01) + es1);
  float r2 = __builtin_amdgcn_rcpf(__low2float(lp23) + es2);
  float r3 = __builtin_amdgcn_rcpf(__high2float(lp23) + es3);

  // head-average + bias; lane i holds channels 4i..4i+3
  float4 b4 = *(const float4*)(bias + 4*i);
  float o0 = 0.25f*(__low2float(acc[0])*r0 + __high2float(acc[0])*r1 +
                    __low2float(acc[1])*r2 + __high2float(acc[1])*r3) + b4.x;
  float o1 = 0.25f*(__low2float(acc[2])*r0 + __high2float(acc[2])*r1 +
                    __low2float(acc[3])*r2 + __high2float(acc[3])*r3) + b4.y;
  float o2 = 0.25f*(__low2float(acc[4])*r0 + __high2float(acc[4])*r1 +
                    __low2float(acc[5])*r2 + __high2float(acc[5])*r3) + b4.z;
  float o3 = 0.25f*(__low2float(acc[6])*r0 + __high2float(acc[6])*r1 +
                    __low2float(acc[7])*r2 + __high2float(acc[7])*r3) + b4.w;

  // LayerNorm (each channel appears 4x across the wave)
  float s  = wsum(o0 + o1 + o2 + o3) * 0.25f;
  float sq = wsum(o0*o0 + o1*o1 + o2*o2 + o3*o3) * 0.25f;
  float mu = s * (1.f/OUT_DIM);
  float var = sq * (1.f/OUT_DIM) - mu*mu;
  float rs = rsqrtf(var + LN_EPS);
  float4 g4v = *(const float4*)(gamma + 4*i);
  float4 be4 = *(const float4*)(beta + 4*i);
  if (ln < 16){
    float4 ov;
    ov.x = (o0 - mu)*rs*g4v.x + be4.x;
    ov.y = (o1 - mu)*rs*g4v.y + be4.y;
    ov.z = (o2 - mu)*rs*g4v.z + be4.z;
    ov.w = (o3 - mu)*rs*g4v.w + be4.w;
    *(float4*)(out + (size_t)node*OUT_DIM + 4*i) = ov;
  }
}

extern "C" void kernel_launch(void* const* d_in, const int* in_sizes, int n_in,
                              void* d_out, int out_size, void* d_ws, size_t ws_size,
                              hipStream_t stream)
{
  const float* x     = (const float*)d_in[0];
  const int*   ei    = (const int*)d_in[1];
  const float* W     = (const float*)d_in[2];
  const float* att_s = (const float*)d_in[3];
  const float* att_d = (const float*)d_in[4];
  const float* bias  = (const float*)d_in[5];
  const float* gamma = (const float*)d_in[6];
  const float* beta  = (const float*)d_in[7];
  float* out = (float*)d_out;

  int N = in_sizes[0] / IN_DIM;
  int E = in_sizes[1] / 2;

  char* ws = (char*)d_ws;
  __half* xl_t = (__half*)ws;                   ws += (size_t)N*HC*sizeof(__half);
  float* a_src = (float*)ws;                    ws += (size_t)N*HEADS*sizeof(float);
  float* a_dst = (float*)ws;                    ws += (size_t)N*HEADS*sizeof(float);
  int* deg      = (int*)ws;                     ws += (size_t)N*sizeof(int);
  int* cursor   = (int*)ws;                     ws += (size_t)N*sizeof(int);
  int* rowstart = (int*)ws;                     ws += ((size_t)N+1)*sizeof(int);
  int* partial  = (int*)ws;                     ws += 1024*sizeof(int);
  int* csr      = (int*)ws;                     ws += (size_t)E*sizeof(int);
  unsigned short* Wt = (unsigned short*)ws;     ws += (size_t)HC*IN_DIM*sizeof(unsigned short);

  int nb1 = (N + 1023) / 1024;

  k_prep  <<<HC, IN_DIM, 0, stream>>>(W, Wt, deg, N);
  k_gemm_mfma<<<(N + 63)/64, 256, 0, stream>>>(x, Wt, att_s, att_d, xl_t, a_src, a_dst, N);
  k_hist  <<<(E + 255)/256, 256, 0, stream>>>(ei, deg, E);
  k_scan1 <<<nb1, 256, 0, stream>>>(deg, rowstart, partial, N);
  k_scan2 <<<1, 1024, 0, stream>>>(partial, nb1);
  k_scan3 <<<(N + 256)/256, 256, 0, stream>>>(rowstart, partial, cursor, N, E);
  k_fill  <<<(E + 255)/256, 256, 0, stream>>>(ei, cursor, csr, E);
  k_node  <<<(N + 3)/4, 256, 0, stream>>>(rowstart, csr,
            (const float4*)a_src, (const float4*)a_dst, xl_t,
            bias, gamma, beta, out, N);
}

// Round 7
// 248.847 us; speedup vs baseline: 1.6450x; 1.4492x over previous
//
#include <hip/hip_runtime.h>
#include <hip/hip_fp16.h>

#define IN_DIM   128
#define HC       256   // HEADS*OUT_DIM
#define OUT_DIM  64
#define HEADS    4
#define NEG_SLOPE 0.2f
#define LN_EPS   1e-5f
#define MAXBINS  512   // supports N <= 131072 (bin = dst >> 8)
#define SCAT_TPE 16    // edges per thread in k_binscatter (tile = 4096)

typedef short bf16x8 __attribute__((ext_vector_type(8)));
typedef float f32x4  __attribute__((ext_vector_type(4)));

__device__ __forceinline__ float lrelu(float a){ return a > 0.f ? a : NEG_SLOPE * a; }

__device__ __forceinline__ unsigned short f2bf(float f){
  unsigned u = __float_as_uint(f);
  u = u + 0x7fffu + ((u >> 16) & 1u);   // round-to-nearest-even
  return (unsigned short)(u >> 16);
}
__device__ __forceinline__ unsigned pk2(float a, float b){
  return (unsigned)f2bf(a) | ((unsigned)f2bf(b) << 16);
}
__device__ __forceinline__ __half2 u2h(unsigned u){ return *(__half2*)&u; }
__device__ __forceinline__ unsigned h2u(__half2 h){ return *(unsigned*)&h; }

__device__ __forceinline__ float wsum(float v){
  #pragma unroll
  for (int o = 32; o; o >>= 1) v += __shfl_xor(v, o);
  return v;
}

// Per-wave int32/int64 layout detection: int64 node ids < 2^31 have zero odd
// 32-bit words; int32 layout would need 32 random node ids == 0 to fool this.
__device__ __forceinline__ bool detect32(const int* ei){
  int ln = threadIdx.x & 63;
  unsigned probe = (ln < 32) ? (unsigned)ei[2*ln + 1] : 0u;
  return __ballot(probe != 0) != 0ull;
}

// Wt[n][k] = bf16(W[k][n]) (MFMA B-frag friendly) + zero bin counters.
__global__ void k_prep(const float* __restrict__ W, unsigned short* __restrict__ Wt,
                       int* bincnt){
  int n = blockIdx.x;          // 0..255
  int k = threadIdx.x;         // 0..127
  Wt[n*IN_DIM + k] = f2bf(W[k*HC + n]);
  int i = blockIdx.x*blockDim.x + threadIdx.x;
  if (i < MAXBINS) bincnt[i] = 0;
}

// MFMA GEMM: xl_t = fp16(x @ W) head-interleaved [node][ch*4+head],
// plus fp32 logits a_src/a_dst from the fp32 accumulators.
// Block: 64 nodes x 256 cols; 4 waves; wave w owns head w. B fragments
// loaded once per block, reused across 4 node sub-tiles.
__global__ __launch_bounds__(256) void k_gemm_mfma(
    const float* __restrict__ x, const unsigned short* __restrict__ Wt,
    const float* __restrict__ att_s, const float* __restrict__ att_d,
    __half* __restrict__ xl_t, float* __restrict__ a_src,
    float* __restrict__ a_dst, int N)
{
  __shared__ unsigned short sxa[64*IN_DIM];   // 16KB bf16 x-tile, XOR-swizzled
  __shared__ unsigned short sxl[64*HC];       // 32KB fp16 output staging
  int t = threadIdx.x;
  int nb = blockIdx.x * 64;

  #pragma unroll
  for (int it = 0; it < 4; ++it){
    int idx = it*256 + t;
    int row = idx >> 4, seg = idx & 15;
    uint4 pk = make_uint4(0,0,0,0);
    if (nb + row < N){
      const float* xr = x + (size_t)(nb + row)*IN_DIM + seg*8;
      float4 f0 = *(const float4*)xr;
      float4 f1 = *(const float4*)(xr + 4);
      pk.x = pk2(f0.x, f0.y); pk.y = pk2(f0.z, f0.w);
      pk.z = pk2(f1.x, f1.y); pk.w = pk2(f1.z, f1.w);
    }
    int byte = (row*256 + seg*16) ^ ((row & 7) << 4);
    *(uint4*)((char*)sxa + byte) = pk;
  }
  __syncthreads();

  int w = t >> 6, l = t & 63;

  bf16x8 bfr[4][4];
  #pragma unroll
  for (int nt = 0; nt < 4; ++nt){
    int col = w*64 + nt*16 + (l & 15);
    #pragma unroll
    for (int ks = 0; ks < 4; ++ks)
      bfr[nt][ks] = *(const bf16x8*)(Wt + (size_t)col*IN_DIM + ks*32 + ((l >> 4) << 3));
  }
  float attS[4], attD[4];
  #pragma unroll
  for (int nt = 0; nt < 4; ++nt){
    attS[nt] = att_s[w*64 + nt*16 + (l & 15)];
    attD[nt] = att_d[w*64 + nt*16 + (l & 15)];
  }

  #pragma unroll
  for (int sub = 0; sub < 4; ++sub){
    bf16x8 afr[4];
    #pragma unroll
    for (int ks = 0; ks < 4; ++ks){
      int row = sub*16 + (l & 15);
      int byte = (row*256 + ks*64 + ((l >> 4) << 4)) ^ ((row & 7) << 4);
      afr[ks] = *(const bf16x8*)((const char*)sxa + byte);
    }
    f32x4 acc[4] = {{0,0,0,0},{0,0,0,0},{0,0,0,0},{0,0,0,0}};
    #pragma unroll
    for (int nt = 0; nt < 4; ++nt)
      #pragma unroll
      for (int ks = 0; ks < 4; ++ks)
        acc[nt] = __builtin_amdgcn_mfma_f32_16x16x32_bf16(afr[ks], bfr[nt][ks], acc[nt], 0, 0, 0);

    #pragma unroll
    for (int r = 0; r < 4; ++r){
      float ps = 0.f, pd = 0.f;
      #pragma unroll
      for (int nt = 0; nt < 4; ++nt){
        ps = fmaf(acc[nt][r], attS[nt], ps);
        pd = fmaf(acc[nt][r], attD[nt], pd);
      }
      #pragma unroll
      for (int o = 8; o; o >>= 1){ ps += __shfl_xor(ps, o); pd += __shfl_xor(pd, o); }
      int node = nb + sub*16 + (l >> 4)*4 + r;
      if ((l & 15) == 0 && node < N){
        a_src[node*4 + w] = ps;
        a_dst[node*4 + w] = pd;
      }
    }

    #pragma unroll
    for (int nt = 0; nt < 4; ++nt){
      int ch = nt*16 + (l & 15);
      #pragma unroll
      for (int r = 0; r < 4; ++r){
        int row = sub*16 + (l >> 4)*4 + r;
        sxl[row*HC + ch*4 + w] = __half_as_ushort(__float2half(acc[nt][r]));
      }
    }
  }
  __syncthreads();
  const uint4* s4 = (const uint4*)sxl;
  uint4* g4 = (uint4*)(xl_t + (size_t)nb*HC);
  for (int c = t; c < 2048; c += 256){
    int row = c >> 5;
    if (nb + row < N) g4[c] = s4[c];
  }
}

// ---- CSR build, bucketed (bin = dst >> 8, 256 dsts per bin) ----

// Per-block LDS histogram of bins; one global atomic per (bin, block).
__global__ __launch_bounds__(256) void k_bincount(const int* ei, int* bincnt,
                                                  int E, int nbins){
  __shared__ int h[MAXBINS];
  bool i32 = detect32(ei);
  for (int i = threadIdx.x; i < nbins; i += 256) h[i] = 0;
  __syncthreads();
  int idx = blockIdx.x*blockDim.x + threadIdx.x;
  int stride = gridDim.x*blockDim.x;
  for (int e = idx; e < E; e += stride){
    int d = i32 ? ei[E + e] : (int)((const long long*)ei)[(size_t)E + e];
    atomicAdd(&h[d >> 8], 1);
  }
  __syncthreads();
  for (int i = threadIdx.x; i < nbins; i += 256)
    if (h[i]) atomicAdd(&bincnt[i], h[i]);
}

// Single-block exclusive scan of bin counts; also rowstart[N] = E.
__global__ __launch_bounds__(512) void k_binscan(const int* __restrict__ bincnt,
    int* binstart, int* bincur, int* rowstart, int nbins, int N, int E){
  __shared__ int sh[512];
  int tid = threadIdx.x;
  int v = (tid < nbins) ? bincnt[tid] : 0;
  sh[tid] = v; __syncthreads();
  #pragma unroll
  for (int off = 1; off < 512; off <<= 1){
    int t = (tid >= off) ? sh[tid-off] : 0;
    __syncthreads();
    sh[tid] += t;
    __syncthreads();
  }
  int ex = sh[tid] - v;
  if (tid < nbins){ binstart[tid] = ex; bincur[tid] = ex; }
  if (tid == 0){ binstart[nbins] = E; rowstart[N] = E; }
}

// Partition edges into bin segments. Intra-tile rank via LDS atomics, one
// global atomic per (bin, tile), grouped writes (runs of consecutive words).
// tmp word = src | (dst&255)<<20  (requires N < 2^20).
__global__ __launch_bounds__(256) void k_binscatter(const int* ei, int* bincur,
    unsigned* tmp, int E, int nbins){
  __shared__ int h[MAXBINS];
  __shared__ int base[MAXBINS];
  bool i32 = detect32(ei);
  int tile0 = blockIdx.x * (256*SCAT_TPE);
  for (int i = threadIdx.x; i < nbins; i += 256) h[i] = 0;
  __syncthreads();
  unsigned pk[SCAT_TPE]; int rk[SCAT_TPE];
  #pragma unroll
  for (int k = 0; k < SCAT_TPE; ++k){
    int e = tile0 + k*256 + threadIdx.x;
    if (e < E){
      int s, d;
      if (i32){ s = ei[e]; d = ei[E + e]; }
      else {
        s = (int)((const long long*)ei)[e];
        d = (int)((const long long*)ei)[(size_t)E + e];
      }
      int b = d >> 8;
      pk[k] = (unsigned)s | ((unsigned)(d & 255) << 20);
      rk[k] = atomicAdd(&h[b], 1) | (b << 16);
    }
  }
  __syncthreads();
  for (int i = threadIdx.x; i < nbins; i += 256)
    base[i] = h[i] ? atomicAdd(&bincur[i], h[i]) : 0;
  __syncthreads();
  #pragma unroll
  for (int k = 0; k < SCAT_TPE; ++k){
    int e = tile0 + k*256 + threadIdx.x;
    if (e < E){
      int b = rk[k] >> 16, r = rk[k] & 0xFFFF;
      tmp[base[b] + r] = pk[k];
    }
  }
}

// One block per bin: per-dst counts + scan inside the bin -> rowstart
// (coalesced) and csr (scatter confined to the bin's L2-hot 16KB segment).
__global__ __launch_bounds__(256) void k_binsort(const unsigned* __restrict__ tmp,
    const int* __restrict__ binstart, int* rowstart, int* csr, int N){
  __shared__ int c[256], c2[256], sc[256];
  int b = blockIdx.x, tid = threadIdx.x;
  int s0 = binstart[b], s1 = binstart[b+1];
  c[tid] = 0; c2[tid] = 0;
  __syncthreads();
  for (int e = s0 + tid; e < s1; e += 256)
    atomicAdd(&c[(tmp[e] >> 20) & 255], 1);
  __syncthreads();
  int v = c[tid]; sc[tid] = v;
  __syncthreads();
  #pragma unroll
  for (int off = 1; off < 256; off <<= 1){
    int t = (tid >= off) ? sc[tid-off] : 0;
    __syncthreads();
    sc[tid] += t;
    __syncthreads();
  }
  int ex = sc[tid] - v;
  int d = b*256 + tid;
  if (d < N) rowstart[d] = s0 + ex;
  sc[tid] = ex;
  __syncthreads();
  for (int e = s0 + tid; e < s1; e += 256){
    unsigned u = tmp[e];
    int dl = (u >> 20) & 255;
    int pos = s0 + sc[dl] + atomicAdd(&c2[dl], 1);
    csr[pos] = (int)(u & 0xFFFFFu);
  }
}

// One wave per destination node. Direct softmax (logits O(1) -> exp safe in
// f32; shift-invariance). Phase A (lane=edge): exp weights packed fp16 to LDS.
// Phase B: 4 groups of 16 lanes, one edge per group; lane covers 32B
// (16 fp16 = 4ch x 4heads); 8 v_pk_fma_f16 per 4 edges.
__global__ __launch_bounds__(256) void k_node(
    const int* __restrict__ rowstart, const int* __restrict__ csr,
    const float4* __restrict__ a_src4, const float4* __restrict__ a_dst4,
    const __half* __restrict__ xl_t,
    const float* __restrict__ bias, const float* __restrict__ gamma,
    const float* __restrict__ beta, float* __restrict__ out, int N)
{
  __shared__ uint2 wlds[4][64];
  __shared__ int   slds[4][64];
  int wv = threadIdx.x >> 6, ln = threadIdx.x & 63;
  int node = blockIdx.x*4 + wv;
  if (node >= N) return;
  int g = ln >> 4, i = ln & 15;

  int start = rowstart[node], end = rowstart[node+1];
  float4 ad = a_dst4[node];
  float4 asl = a_src4[node];

  float es0 = __expf(lrelu(asl.x + ad.x));
  float es1 = __expf(lrelu(asl.y + ad.y));
  float es2 = __expf(lrelu(asl.z + ad.z));
  float es3 = __expf(lrelu(asl.w + ad.w));

  __half2 acc[8];
  #pragma unroll
  for (int m = 0; m < 8; ++m) acc[m] = __float2half2_rn(0.f);
  float lp0 = 0.f, lp1 = 0.f, lp2 = 0.f, lp3 = 0.f;

  for (int t = start; t < end; t += 64){
    int nt = end - t; if (nt > 64) nt = 64;
    int sid = 0;
    float e0 = 0.f, e1 = 0.f, e2 = 0.f, e3 = 0.f;
    if (ln < nt){
      sid = csr[t + ln];
      float4 as4 = a_src4[sid];
      e0 = __expf(lrelu(as4.x + ad.x));
      e1 = __expf(lrelu(as4.y + ad.y));
      e2 = __expf(lrelu(as4.z + ad.z));
      e3 = __expf(lrelu(as4.w + ad.w));
      lp0 += e0; lp1 += e1; lp2 += e2; lp3 += e3;
    }
    wlds[wv][ln] = make_uint2(h2u(__floats2half2_rn(e0, e1)),
                              h2u(__floats2half2_rn(e2, e3)));
    slds[wv][ln] = sid;

    int nwin = (nt + 3) >> 2;
    for (int j = 0; j < nwin; ++j){
      int e = j*4 + g;
      uint2 wpk = wlds[wv][e];
      int sj = slds[wv][e];
      __half2 w01 = u2h(wpk.x), w23 = u2h(wpk.y);
      const uint4* p = (const uint4*)((const char*)xl_t + ((size_t)sj*512 + (i << 5)));
      uint4 xa = p[0], xb = p[1];
      acc[0] = __hfma2(w01, u2h(xa.x), acc[0]);
      acc[1] = __hfma2(w23, u2h(xa.y), acc[1]);
      acc[2] = __hfma2(w01, u2h(xa.z), acc[2]);
      acc[3] = __hfma2(w23, u2h(xa.w), acc[3]);
      acc[4] = __hfma2(w01, u2h(xb.x), acc[4]);
      acc[5] = __hfma2(w23, u2h(xb.y), acc[5]);
      acc[6] = __hfma2(w01, u2h(xb.z), acc[6]);
      acc[7] = __hfma2(w23, u2h(xb.w), acc[7]);
    }
  }

  #pragma unroll
  for (int m = 0; m < 8; ++m){
    acc[m] = __hadd2(acc[m], u2h(__shfl_xor(h2u(acc[m]), 16)));
    acc[m] = __hadd2(acc[m], u2h(__shfl_xor(h2u(acc[m]), 32)));
  }

  {
    __half2 s01 = __floats2half2_rn(es0, es1);
    __half2 s23 = __floats2half2_rn(es2, es3);
    const uint4* p = (const uint4*)((const char*)xl_t + ((size_t)node*512 + (i << 5)));
    uint4 xa = p[0], xb = p[1];
    acc[0] = __hfma2(s01, u2h(xa.x), acc[0]);
    acc[1] = __hfma2(s23, u2h(xa.y), acc[1]);
    acc[2] = __hfma2(s01, u2h(xa.z), acc[2]);
    acc[3] = __hfma2(s23, u2h(xa.w), acc[3]);
    acc[4] = __hfma2(s01, u2h(xb.x), acc[4]);
    acc[5] = __hfma2(s23, u2h(xb.y), acc[5]);
    acc[6] = __hfma2(s01, u2h(xb.z), acc[6]);
    acc[7] = __hfma2(s23, u2h(xb.w), acc[7]);
  }

  __half2 lp01 = __floats2half2_rn(lp0, lp1);
  __half2 lp23 = __floats2half2_rn(lp2, lp3);
  #pragma unroll
  for (int o = 32; o; o >>= 1){
    lp01 = __hadd2(lp01, u2h(__shfl_xor(h2u(lp01), o)));
    lp23 = __hadd2(lp23, u2h(__shfl_xor(h2u(lp23), o)));
  }
  float r0 = __builtin_amdgcn_rcpf(__low2float(lp01) + es0);
  float r1 = __builtin_amdgcn_rcpf(__high2float(lp01) + es1);
  float r2 = __builtin_amdgcn_rcpf(__low2float(lp23) + es2);
  float r3 = __builtin_amdgcn_rcpf(__high2float(lp23) + es3);

  float4 b4 = *(const float4*)(bias + 4*i);
  float o0 = 0.25f*(__low2float(acc[0])*r0 + __high2float(acc[0])*r1 +
                    __low2float(acc[1])*r2 + __high2float(acc[1])*r3) + b4.x;
  float o1 = 0.25f*(__low2float(acc[2])*r0 + __high2float(acc[2])*r1 +
                    __low2float(acc[3])*r2 + __high2float(acc[3])*r3) + b4.y;
  float o2 = 0.25f*(__low2float(acc[4])*r0 + __high2float(acc[4])*r1 +
                    __low2float(acc[5])*r2 + __high2float(acc[5])*r3) + b4.z;
  float o3 = 0.25f*(__low2float(acc[6])*r0 + __high2float(acc[6])*r1 +
                    __low2float(acc[7])*r2 + __high2float(acc[7])*r3) + b4.w;

  float s  = wsum(o0 + o1 + o2 + o3) * 0.25f;
  float sq = wsum(o0*o0 + o1*o1 + o2*o2 + o3*o3) * 0.25f;
  float mu = s * (1.f/OUT_DIM);
  float var = sq * (1.f/OUT_DIM) - mu*mu;
  float rs = rsqrtf(var + LN_EPS);
  float4 g4v = *(const float4*)(gamma + 4*i);
  float4 be4 = *(const float4*)(beta + 4*i);
  if (ln < 16){
    float4 ov;
    ov.x = (o0 - mu)*rs*g4v.x + be4.x;
    ov.y = (o1 - mu)*rs*g4v.y + be4.y;
    ov.z = (o2 - mu)*rs*g4v.z + be4.z;
    ov.w = (o3 - mu)*rs*g4v.w + be4.w;
    *(float4*)(out + (size_t)node*OUT_DIM + 4*i) = ov;
  }
}

extern "C" void kernel_launch(void* const* d_in, const int* in_sizes, int n_in,
                              void* d_out, int out_size, void* d_ws, size_t ws_size,
                              hipStream_t stream)
{
  const float* x     = (const float*)d_in[0];
  const int*   ei    = (const int*)d_in[1];
  const float* W     = (const float*)d_in[2];
  const float* att_s = (const float*)d_in[3];
  const float* att_d = (const float*)d_in[4];
  const float* bias  = (const float*)d_in[5];
  const float* gamma = (const float*)d_in[6];
  const float* beta  = (const float*)d_in[7];
  float* out = (float*)d_out;

  int N = in_sizes[0] / IN_DIM;
  int E = in_sizes[1] / 2;
  int nbins = (N + 255) >> 8;

  char* ws = (char*)d_ws;
  __half* xl_t = (__half*)ws;                   ws += (size_t)N*HC*sizeof(__half);
  float* a_src = (float*)ws;                    ws += (size_t)N*HEADS*sizeof(float);
  float* a_dst = (float*)ws;                    ws += (size_t)N*HEADS*sizeof(float);
  int* rowstart = (int*)ws;                     ws += ((size_t)N+1)*sizeof(int);
  int* csr      = (int*)ws;                     ws += (size_t)E*sizeof(int);
  unsigned* tmp = (unsigned*)ws;                ws += (size_t)E*sizeof(unsigned);
  int* bincnt   = (int*)ws;                     ws += MAXBINS*sizeof(int);
  int* binstart = (int*)ws;                     ws += (MAXBINS+1)*sizeof(int);
  int* bincur   = (int*)ws;                     ws += MAXBINS*sizeof(int);
  unsigned short* Wt = (unsigned short*)ws;     ws += (size_t)HC*IN_DIM*sizeof(unsigned short);

  k_prep     <<<HC, IN_DIM, 0, stream>>>(W, Wt, bincnt);
  k_gemm_mfma<<<(N + 63)/64, 256, 0, stream>>>(x, Wt, att_s, att_d, xl_t, a_src, a_dst, N);
  k_bincount <<<1024, 256, 0, stream>>>(ei, bincnt, E, nbins);
  k_binscan  <<<1, 512, 0, stream>>>(bincnt, binstart, bincur, rowstart, nbins, N, E);
  k_binscatter<<<(E + 256*SCAT_TPE - 1)/(256*SCAT_TPE), 256, 0, stream>>>(ei, bincur, tmp, E, nbins);
  k_binsort  <<<nbins, 256, 0, stream>>>(tmp, binstart, rowstart, csr, N);
  k_node     <<<(N + 3)/4, 256, 0, stream>>>(rowstart, csr,
               (const float4*)a_src, (const float4*)a_dst, xl_t,
               bias, gamma, beta, out, N);
}

// Round 8
// 238.642 us; speedup vs baseline: 1.7154x; 1.0428x over previous
//
#include <hip/hip_runtime.h>
#include <hip/hip_fp16.h>

#define IN_DIM   128
#define HC       256   // HEADS*OUT_DIM
#define OUT_DIM  64
#define HEADS    4
#define NEG_SLOPE 0.2f
#define LN_EPS   1e-5f
#define MAXBINS  512   // supports N <= 131072 (bin = dst >> 8)
#define SCAT_TPE 16    // edges per thread in binscatter (tile = 4096)

typedef short bf16x8 __attribute__((ext_vector_type(8)));
typedef float f32x4  __attribute__((ext_vector_type(4)));

__device__ __forceinline__ float lrelu(float a){ return a > 0.f ? a : NEG_SLOPE * a; }

__device__ __forceinline__ unsigned short f2bf(float f){
  unsigned u = __float_as_uint(f);
  u = u + 0x7fffu + ((u >> 16) & 1u);   // round-to-nearest-even
  return (unsigned short)(u >> 16);
}
__device__ __forceinline__ unsigned pk2(float a, float b){
  return (unsigned)f2bf(a) | ((unsigned)f2bf(b) << 16);
}
__device__ __forceinline__ __half2 u2h(unsigned u){ return *(__half2*)&u; }
__device__ __forceinline__ unsigned h2u(__half2 h){ return *(unsigned*)&h; }

// Per-wave int32/int64 layout detection: int64 node ids < 2^31 have zero odd
// 32-bit words; int32 layout would need 32 random node ids == 0 to fool this.
__device__ __forceinline__ bool detect32(const int* ei){
  int ln = threadIdx.x & 63;
  unsigned probe = (ln < 32) ? (unsigned)ei[2*ln + 1] : 0u;
  return __ballot(probe != 0) != 0ull;
}

// Wt[n][k] = bf16(W[k][n]) (MFMA B-frag friendly) + zero bin counters.
__global__ void k_prep(const float* __restrict__ W, unsigned short* __restrict__ Wt,
                       int* bincnt){
  int n = blockIdx.x;          // 0..255
  int k = threadIdx.x;         // 0..127
  Wt[n*IN_DIM + k] = f2bf(W[k*HC + n]);
  int i = blockIdx.x*blockDim.x + threadIdx.x;
  if (i < MAXBINS) bincnt[i] = 0;
}

// ---- GEMM body (MFMA): xl_t = fp16(x@W) head-interleaved + logits ----
__device__ __forceinline__ void gemm_body(int bid, char* smem,
    const float* __restrict__ x, const unsigned short* __restrict__ Wt,
    const float* __restrict__ att_s, const float* __restrict__ att_d,
    __half* __restrict__ xl_t, float* __restrict__ a_src,
    float* __restrict__ a_dst, int N)
{
  unsigned short* sxa = (unsigned short*)smem;            // 16KB, XOR-swizzled
  unsigned short* sxl = (unsigned short*)(smem + 16384);  // 32KB staging
  int t = threadIdx.x;
  int nb = bid * 64;

  #pragma unroll
  for (int it = 0; it < 4; ++it){
    int idx = it*256 + t;
    int row = idx >> 4, seg = idx & 15;
    uint4 pk = make_uint4(0,0,0,0);
    if (nb + row < N){
      const float* xr = x + (size_t)(nb + row)*IN_DIM + seg*8;
      float4 f0 = *(const float4*)xr;
      float4 f1 = *(const float4*)(xr + 4);
      pk.x = pk2(f0.x, f0.y); pk.y = pk2(f0.z, f0.w);
      pk.z = pk2(f1.x, f1.y); pk.w = pk2(f1.z, f1.w);
    }
    int byte = (row*256 + seg*16) ^ ((row & 7) << 4);
    *(uint4*)(smem + byte) = pk;
  }
  __syncthreads();

  int w = t >> 6, l = t & 63;

  bf16x8 bfr[4][4];
  #pragma unroll
  for (int nt = 0; nt < 4; ++nt){
    int col = w*64 + nt*16 + (l & 15);
    #pragma unroll
    for (int ks = 0; ks < 4; ++ks)
      bfr[nt][ks] = *(const bf16x8*)(Wt + (size_t)col*IN_DIM + ks*32 + ((l >> 4) << 3));
  }
  float attS[4], attD[4];
  #pragma unroll
  for (int nt = 0; nt < 4; ++nt){
    attS[nt] = att_s[w*64 + nt*16 + (l & 15)];
    attD[nt] = att_d[w*64 + nt*16 + (l & 15)];
  }

  #pragma unroll
  for (int sub = 0; sub < 4; ++sub){
    bf16x8 afr[4];
    #pragma unroll
    for (int ks = 0; ks < 4; ++ks){
      int row = sub*16 + (l & 15);
      int byte = (row*256 + ks*64 + ((l >> 4) << 4)) ^ ((row & 7) << 4);
      afr[ks] = *(const bf16x8*)(smem + byte);
    }
    f32x4 acc[4] = {{0,0,0,0},{0,0,0,0},{0,0,0,0},{0,0,0,0}};
    #pragma unroll
    for (int nt = 0; nt < 4; ++nt)
      #pragma unroll
      for (int ks = 0; ks < 4; ++ks)
        acc[nt] = __builtin_amdgcn_mfma_f32_16x16x32_bf16(afr[ks], bfr[nt][ks], acc[nt], 0, 0, 0);

    #pragma unroll
    for (int r = 0; r < 4; ++r){
      float ps = 0.f, pd = 0.f;
      #pragma unroll
      for (int nt = 0; nt < 4; ++nt){
        ps = fmaf(acc[nt][r], attS[nt], ps);
        pd = fmaf(acc[nt][r], attD[nt], pd);
      }
      #pragma unroll
      for (int o = 8; o; o >>= 1){ ps += __shfl_xor(ps, o); pd += __shfl_xor(pd, o); }
      int node = nb + sub*16 + (l >> 4)*4 + r;
      if ((l & 15) == 0 && node < N){
        a_src[node*4 + w] = ps;
        a_dst[node*4 + w] = pd;
      }
    }

    #pragma unroll
    for (int nt = 0; nt < 4; ++nt){
      int ch = nt*16 + (l & 15);
      #pragma unroll
      for (int r = 0; r < 4; ++r){
        int row = sub*16 + (l >> 4)*4 + r;
        sxl[row*HC + ch*4 + w] = __half_as_ushort(__float2half(acc[nt][r]));
      }
    }
  }
  __syncthreads();
  const uint4* s4 = (const uint4*)sxl;
  uint4* g4 = (uint4*)(xl_t + (size_t)nb*HC);
  for (int c = t; c < 2048; c += 256){
    int row = c >> 5;
    if (nb + row < N) g4[c] = s4[c];
  }
}

// ---- binscatter body: partition edges into bin segments ----
// tmp word = src | (dst&255)<<20  (requires N < 2^20).
__device__ __forceinline__ void scat_body(int bid, char* smem,
    const int* ei, int* bincur, unsigned* tmp, int E, int nbins)
{
  int* h    = (int*)smem;           // 2KB
  int* base = (int*)(smem + 2048);  // 2KB
  bool i32 = detect32(ei);
  int tile0 = bid * (256*SCAT_TPE);
  for (int i = threadIdx.x; i < nbins; i += 256) h[i] = 0;
  __syncthreads();
  unsigned pk[SCAT_TPE]; int rk[SCAT_TPE];
  #pragma unroll
  for (int k = 0; k < SCAT_TPE; ++k){
    int e = tile0 + k*256 + threadIdx.x;
    if (e < E){
      int s, d;
      if (i32){ s = ei[e]; d = ei[E + e]; }
      else {
        s = (int)((const long long*)ei)[e];
        d = (int)((const long long*)ei)[(size_t)E + e];
      }
      int b = d >> 8;
      pk[k] = (unsigned)s | ((unsigned)(d & 255) << 20);
      rk[k] = atomicAdd(&h[b], 1) | (b << 16);
    }
  }
  __syncthreads();
  for (int i = threadIdx.x; i < nbins; i += 256)
    base[i] = h[i] ? atomicAdd(&bincur[i], h[i]) : 0;
  __syncthreads();
  #pragma unroll
  for (int k = 0; k < SCAT_TPE; ++k){
    int e = tile0 + k*256 + threadIdx.x;
    if (e < E){
      int b = rk[k] >> 16, r = rk[k] & 0xFFFF;
      tmp[base[b] + r] = pk[k];
    }
  }
}

// Fused dispatch: gemm blocks [0, gemmBlocks), binscatter blocks after.
// Independent work overlaps on the GPU instead of serializing on the stream.
__global__ __launch_bounds__(256) void k_gemm_scat(
    const float* __restrict__ x, const unsigned short* __restrict__ Wt,
    const float* __restrict__ att_s, const float* __restrict__ att_d,
    __half* __restrict__ xl_t, float* __restrict__ a_src, float* __restrict__ a_dst,
    int N, const int* ei, int* bincur, unsigned* tmp, int E, int nbins,
    int gemmBlocks)
{
  __shared__ char smem[49152];
  int bid = (int)blockIdx.x;
  if (bid < gemmBlocks)
    gemm_body(bid, smem, x, Wt, att_s, att_d, xl_t, a_src, a_dst, N);
  else
    scat_body(bid - gemmBlocks, smem, ei, bincur, tmp, E, nbins);
}

// Per-block LDS histogram of bins; one global atomic per (bin, block).
__global__ __launch_bounds__(256) void k_bincount(const int* ei, int* bincnt,
                                                  int E, int nbins){
  __shared__ int h[MAXBINS];
  bool i32 = detect32(ei);
  for (int i = threadIdx.x; i < nbins; i += 256) h[i] = 0;
  __syncthreads();
  int idx = blockIdx.x*blockDim.x + threadIdx.x;
  int stride = gridDim.x*blockDim.x;
  for (int e = idx; e < E; e += stride){
    int d = i32 ? ei[E + e] : (int)((const long long*)ei)[(size_t)E + e];
    atomicAdd(&h[d >> 8], 1);
  }
  __syncthreads();
  for (int i = threadIdx.x; i < nbins; i += 256)
    if (h[i]) atomicAdd(&bincnt[i], h[i]);
}

// Single-block exclusive scan of bin counts; also rowstart[N] = E.
__global__ __launch_bounds__(512) void k_binscan(const int* __restrict__ bincnt,
    int* binstart, int* bincur, int* rowstart, int nbins, int N, int E){
  __shared__ int sh[512];
  int tid = threadIdx.x;
  int v = (tid < nbins) ? bincnt[tid] : 0;
  sh[tid] = v; __syncthreads();
  #pragma unroll
  for (int off = 1; off < 512; off <<= 1){
    int t = (tid >= off) ? sh[tid-off] : 0;
    __syncthreads();
    sh[tid] += t;
    __syncthreads();
  }
  int ex = sh[tid] - v;
  if (tid < nbins){ binstart[tid] = ex; bincur[tid] = ex; }
  if (tid == 0){ binstart[nbins] = E; rowstart[N] = E; }
}

// One block per bin: per-dst counts + scan -> rowstart, csr.
__global__ __launch_bounds__(256) void k_binsort(const unsigned* __restrict__ tmp,
    const int* __restrict__ binstart, int* rowstart, int* csr, int N){
  __shared__ int c[256], c2[256], sc[256];
  int b = blockIdx.x, tid = threadIdx.x;
  int s0 = binstart[b], s1 = binstart[b+1];
  c[tid] = 0; c2[tid] = 0;
  __syncthreads();
  for (int e = s0 + tid; e < s1; e += 256)
    atomicAdd(&c[(tmp[e] >> 20) & 255], 1);
  __syncthreads();
  int v = c[tid]; sc[tid] = v;
  __syncthreads();
  #pragma unroll
  for (int off = 1; off < 256; off <<= 1){
    int t = (tid >= off) ? sc[tid-off] : 0;
    __syncthreads();
    sc[tid] += t;
    __syncthreads();
  }
  int ex = sc[tid] - v;
  int d = b*256 + tid;
  if (d < N) rowstart[d] = s0 + ex;
  sc[tid] = ex;
  __syncthreads();
  for (int e = s0 + tid; e < s1; e += 256){
    unsigned u = tmp[e];
    int dl = (u >> 20) & 255;
    int pos = s0 + sc[dl] + atomicAdd(&c2[dl], 1);
    csr[pos] = (int)(u & 0xFFFFFu);
  }
}

// One 16-lane GROUP per destination node (4 nodes/wave, 16 nodes/block).
// Direct softmax (logits O(1), shift-invariance). Per <=16-edge chunk:
// phase A on 16 lanes (exp weights -> LDS), then PV: group gathers one full
// 512B fp16 row per edge (lane i covers 32B = 4ch x 4heads), 8 v_pk_fma_f16.
// No cross-group combine; denom + LN reduce width-16.
__global__ __launch_bounds__(256) void k_node(
    const int* __restrict__ rowstart, const int* __restrict__ csr,
    const float4* __restrict__ a_src4, const float4* __restrict__ a_dst4,
    const __half* __restrict__ xl_t,
    const float* __restrict__ bias, const float* __restrict__ gamma,
    const float* __restrict__ beta, float* __restrict__ out, int N)
{
  __shared__ uint2 wlds[4][4][16];
  __shared__ int   slds[4][4][16];
  int wv = threadIdx.x >> 6, ln = threadIdx.x & 63;
  int g = ln >> 4, i = ln & 15;
  int node = blockIdx.x*16 + wv*4 + g;
  bool alive = node < N;
  int nc = alive ? node : N-1;

  int start = rowstart[nc];
  int end   = alive ? rowstart[nc+1] : start;
  float4 ad  = a_dst4[nc];
  float4 asl = a_src4[nc];

  float es0 = __expf(lrelu(asl.x + ad.x));
  float es1 = __expf(lrelu(asl.y + ad.y));
  float es2 = __expf(lrelu(asl.z + ad.z));
  float es3 = __expf(lrelu(asl.w + ad.w));

  // self-loop init
  __half2 s01 = __floats2half2_rn(es0, es1);
  __half2 s23 = __floats2half2_rn(es2, es3);
  const uint4* ps = (const uint4*)((const char*)xl_t + ((size_t)nc*512 + (i << 5)));
  uint4 xa = ps[0], xb = ps[1];
  __half2 acc[8];
  acc[0] = __hmul2(s01, u2h(xa.x));
  acc[1] = __hmul2(s23, u2h(xa.y));
  acc[2] = __hmul2(s01, u2h(xa.z));
  acc[3] = __hmul2(s23, u2h(xa.w));
  acc[4] = __hmul2(s01, u2h(xb.x));
  acc[5] = __hmul2(s23, u2h(xb.y));
  acc[6] = __hmul2(s01, u2h(xb.z));
  acc[7] = __hmul2(s23, u2h(xb.w));
  float lp0 = 0.f, lp1 = 0.f, lp2 = 0.f, lp3 = 0.f;

  for (int t = start; ; t += 16){
    int rem = end - t;
    rem = rem < 0 ? 0 : (rem > 16 ? 16 : rem);
    int rmax = rem;
    rmax = max(rmax, __shfl_xor(rmax, 16));
    rmax = max(rmax, __shfl_xor(rmax, 32));
    if (rmax == 0) break;

    int sid = 0;
    float e0 = 0.f, e1 = 0.f, e2 = 0.f, e3 = 0.f;
    if (i < rem){
      sid = csr[t + i];
      float4 as4 = a_src4[sid];
      e0 = __expf(lrelu(as4.x + ad.x));
      e1 = __expf(lrelu(as4.y + ad.y));
      e2 = __expf(lrelu(as4.z + ad.z));
      e3 = __expf(lrelu(as4.w + ad.w));
      lp0 += e0; lp1 += e1; lp2 += e2; lp3 += e3;
    }
    wlds[wv][g][i] = make_uint2(h2u(__floats2half2_rn(e0, e1)),
                                h2u(__floats2half2_rn(e2, e3)));
    slds[wv][g][i] = sid;

    #pragma unroll 2
    for (int j = 0; j < rmax; ++j){
      if (j < rem){
        uint2 wpk = wlds[wv][g][j];
        int sj = slds[wv][g][j];
        __half2 w01 = u2h(wpk.x), w23 = u2h(wpk.y);
        const uint4* p = (const uint4*)((const char*)xl_t + ((size_t)sj*512 + (i << 5)));
        uint4 ya = p[0], yb = p[1];
        acc[0] = __hfma2(w01, u2h(ya.x), acc[0]);
        acc[1] = __hfma2(w23, u2h(ya.y), acc[1]);
        acc[2] = __hfma2(w01, u2h(ya.z), acc[2]);
        acc[3] = __hfma2(w23, u2h(ya.w), acc[3]);
        acc[4] = __hfma2(w01, u2h(yb.x), acc[4]);
        acc[5] = __hfma2(w23, u2h(yb.y), acc[5]);
        acc[6] = __hfma2(w01, u2h(yb.z), acc[6]);
        acc[7] = __hfma2(w23, u2h(yb.w), acc[7]);
      }
    }
  }

  // denominators: packed reduce within the 16-lane group
  __half2 lp01 = __floats2half2_rn(lp0, lp1);
  __half2 lp23 = __floats2half2_rn(lp2, lp3);
  #pragma unroll
  for (int o = 8; o; o >>= 1){
    lp01 = __hadd2(lp01, u2h(__shfl_xor(h2u(lp01), o)));
    lp23 = __hadd2(lp23, u2h(__shfl_xor(h2u(lp23), o)));
  }
  float r0 = __builtin_amdgcn_rcpf(__low2float(lp01) + es0);
  float r1 = __builtin_amdgcn_rcpf(__high2float(lp01) + es1);
  float r2 = __builtin_amdgcn_rcpf(__low2float(lp23) + es2);
  float r3 = __builtin_amdgcn_rcpf(__high2float(lp23) + es3);

  // head-average + bias; lane i holds channels 4i..4i+3
  float4 b4 = *(const float4*)(bias + 4*i);
  float o0 = 0.25f*(__low2float(acc[0])*r0 + __high2float(acc[0])*r1 +
                    __low2float(acc[1])*r2 + __high2float(acc[1])*r3) + b4.x;
  float o1 = 0.25f*(__low2float(acc[2])*r0 + __high2float(acc[2])*r1 +
                    __low2float(acc[3])*r2 + __high2float(acc[3])*r3) + b4.y;
  float o2 = 0.25f*(__low2float(acc[4])*r0 + __high2float(acc[4])*r1 +
                    __low2float(acc[5])*r2 + __high2float(acc[5])*r3) + b4.z;
  float o3 = 0.25f*(__low2float(acc[6])*r0 + __high2float(acc[6])*r1 +
                    __low2float(acc[7])*r2 + __high2float(acc[7])*r3) + b4.w;

  // LayerNorm over the 64 channels held across the 16-lane group
  float s  = o0 + o1 + o2 + o3;
  float sq = o0*o0 + o1*o1 + o2*o2 + o3*o3;
  #pragma unroll
  for (int o = 8; o; o >>= 1){
    s  += __shfl_xor(s, o);
    sq += __shfl_xor(sq, o);
  }
  float mu = s * (1.f/OUT_DIM);
  float var = sq * (1.f/OUT_DIM) - mu*mu;
  float rs = rsqrtf(var + LN_EPS);
  float4 g4v = *(const float4*)(gamma + 4*i);
  float4 be4 = *(const float4*)(beta + 4*i);
  if (alive){
    float4 ov;
    ov.x = (o0 - mu)*rs*g4v.x + be4.x;
    ov.y = (o1 - mu)*rs*g4v.y + be4.y;
    ov.z = (o2 - mu)*rs*g4v.z + be4.z;
    ov.w = (o3 - mu)*rs*g4v.w + be4.w;
    *(float4*)(out + (size_t)node*OUT_DIM + 4*i) = ov;
  }
}

extern "C" void kernel_launch(void* const* d_in, const int* in_sizes, int n_in,
                              void* d_out, int out_size, void* d_ws, size_t ws_size,
                              hipStream_t stream)
{
  const float* x     = (const float*)d_in[0];
  const int*   ei    = (const int*)d_in[1];
  const float* W     = (const float*)d_in[2];
  const float* att_s = (const float*)d_in[3];
  const float* att_d = (const float*)d_in[4];
  const float* bias  = (const float*)d_in[5];
  const float* gamma = (const float*)d_in[6];
  const float* beta  = (const float*)d_in[7];
  float* out = (float*)d_out;

  int N = in_sizes[0] / IN_DIM;
  int E = in_sizes[1] / 2;
  int nbins = (N + 255) >> 8;

  char* ws = (char*)d_ws;
  __half* xl_t = (__half*)ws;                   ws += (size_t)N*HC*sizeof(__half);
  float* a_src = (float*)ws;                    ws += (size_t)N*HEADS*sizeof(float);
  float* a_dst = (float*)ws;                    ws += (size_t)N*HEADS*sizeof(float);
  int* rowstart = (int*)ws;                     ws += ((size_t)N+1)*sizeof(int);
  int* csr      = (int*)ws;                     ws += (size_t)E*sizeof(int);
  unsigned* tmp = (unsigned*)ws;                ws += (size_t)E*sizeof(unsigned);
  int* bincnt   = (int*)ws;                     ws += MAXBINS*sizeof(int);
  int* binstart = (int*)ws;                     ws += (MAXBINS+1)*sizeof(int);
  int* bincur   = (int*)ws;                     ws += MAXBINS*sizeof(int);
  unsigned short* Wt = (unsigned short*)ws;     ws += (size_t)HC*IN_DIM*sizeof(unsigned short);

  int gemmBlocks = (N + 63)/64;
  int scatBlocks = (E + 256*SCAT_TPE - 1)/(256*SCAT_TPE);

  k_prep    <<<HC, IN_DIM, 0, stream>>>(W, Wt, bincnt);
  k_bincount<<<1024, 256, 0, stream>>>(ei, bincnt, E, nbins);
  k_binscan <<<1, 512, 0, stream>>>(bincnt, binstart, bincur, rowstart, nbins, N, E);
  k_gemm_scat<<<gemmBlocks + scatBlocks, 256, 0, stream>>>(
      x, Wt, att_s, att_d, xl_t, a_src, a_dst, N, ei, bincur, tmp, E, nbins,
      gemmBlocks);
  k_binsort <<<nbins, 256, 0, stream>>>(tmp, binstart, rowstart, csr, N);
  k_node    <<<(N + 15)/16, 256, 0, stream>>>(rowstart, csr,
              (const float4*)a_src, (const float4*)a_dst, xl_t,
              bias, gamma, beta, out, N);
}

// Round 9
// 221.832 us; speedup vs baseline: 1.8454x; 1.0758x over previous
//
#include <hip/hip_runtime.h>
#include <hip/hip_fp16.h>

#define IN_DIM   128
#define HC       256   // HEADS*OUT_DIM
#define OUT_DIM  64
#define HEADS    4
#define NEG_SLOPE 0.2f
#define LN_EPS   1e-5f
#define MAXBINS  512   // supports N <= 131072 (bin = dst >> 8)
#define NHIST    128   // partial-histogram blocks in k_front
#define SCAT_TPE 16    // edges per thread in binscatter (tile = 4096)

typedef short bf16x8 __attribute__((ext_vector_type(8)));
typedef float f32x4  __attribute__((ext_vector_type(4)));

__device__ __forceinline__ float lrelu(float a){ return a > 0.f ? a : NEG_SLOPE * a; }

__device__ __forceinline__ unsigned short f2bf(float f){
  unsigned u = __float_as_uint(f);
  u = u + 0x7fffu + ((u >> 16) & 1u);   // round-to-nearest-even
  return (unsigned short)(u >> 16);
}
__device__ __forceinline__ unsigned pk2(float a, float b){
  return (unsigned)f2bf(a) | ((unsigned)f2bf(b) << 16);
}
__device__ __forceinline__ __half2 u2h(unsigned u){ return *(__half2*)&u; }
__device__ __forceinline__ unsigned h2u(__half2 h){ return *(unsigned*)&h; }

// Per-wave int32/int64 layout detection: int64 node ids < 2^31 have zero odd
// 32-bit words; int32 layout would need 32 random node ids == 0 to fool this.
__device__ __forceinline__ bool detect32(const int* ei){
  int ln = threadIdx.x & 63;
  unsigned probe = (ln < 32) ? (unsigned)ei[2*ln + 1] : 0u;
  return __ballot(probe != 0) != 0ull;
}

// Fused front-end: blocks [0,128) transpose W -> Wt (bf16, MFMA B-frag
// friendly); blocks [128, 128+NHIST) build per-slot partial bin histograms
// (no global pre-zeroing needed -> no dependency, full overlap).
__global__ __launch_bounds__(256) void k_front(
    const float* __restrict__ W, unsigned short* __restrict__ Wt,
    const int* ei, int* __restrict__ partials, int E, int nbins)
{
  if (blockIdx.x < 128){
    int n = blockIdx.x*2 + (threadIdx.x >> 7);
    int k = threadIdx.x & 127;
    Wt[n*IN_DIM + k] = f2bf(W[k*HC + n]);
    return;
  }
  __shared__ int h[MAXBINS];
  bool i32 = detect32(ei);
  for (int i = threadIdx.x; i < nbins; i += 256) h[i] = 0;
  __syncthreads();
  int slot = blockIdx.x - 128;
  if (i32){
    const int* dstp = ei + E;
    for (int e = slot*256 + threadIdx.x; e < E; e += NHIST*256)
      atomicAdd(&h[dstp[e] >> 8], 1);
  } else {
    const long long* dstp = (const long long*)ei + E;
    for (int e = slot*256 + threadIdx.x; e < E; e += NHIST*256)
      atomicAdd(&h[(int)dstp[e] >> 8], 1);
  }
  __syncthreads();
  for (int i = threadIdx.x; i < nbins; i += 256)
    partials[slot*MAXBINS + i] = h[i];
}

// Single block: sum partials per bin (coalesced), exclusive scan,
// write binstart/bincur; rowstart[N] = E.
__global__ __launch_bounds__(512) void k_binscan(const int* __restrict__ partials,
    int* binstart, int* bincur, int* rowstart, int nbins, int N, int E){
  __shared__ int sh[512];
  int tid = threadIdx.x;
  int v = 0;
  if (tid < nbins)
    for (int j = 0; j < NHIST; ++j) v += partials[j*MAXBINS + tid];
  sh[tid] = v; __syncthreads();
  #pragma unroll
  for (int off = 1; off < 512; off <<= 1){
    int t = (tid >= off) ? sh[tid-off] : 0;
    __syncthreads();
    sh[tid] += t;
    __syncthreads();
  }
  int ex = sh[tid] - v;
  if (tid < nbins){ binstart[tid] = ex; bincur[tid] = ex; }
  if (tid == 0){ binstart[nbins] = E; rowstart[N] = E; }
}

// ---- GEMM body (MFMA): xl_t = fp16(x@W) head-interleaved + logits ----
__device__ __forceinline__ void gemm_body(int bid, char* smem,
    const float* __restrict__ x, const unsigned short* __restrict__ Wt,
    const float* __restrict__ att_s, const float* __restrict__ att_d,
    __half* __restrict__ xl_t, float* __restrict__ a_src,
    float* __restrict__ a_dst, int N)
{
  unsigned short* sxl = (unsigned short*)(smem + 16384);  // 32KB staging
  int t = threadIdx.x;
  int nb = bid * 64;

  #pragma unroll
  for (int it = 0; it < 4; ++it){
    int idx = it*256 + t;
    int row = idx >> 4, seg = idx & 15;
    uint4 pk = make_uint4(0,0,0,0);
    if (nb + row < N){
      const float* xr = x + (size_t)(nb + row)*IN_DIM + seg*8;
      float4 f0 = *(const float4*)xr;
      float4 f1 = *(const float4*)(xr + 4);
      pk.x = pk2(f0.x, f0.y); pk.y = pk2(f0.z, f0.w);
      pk.z = pk2(f1.x, f1.y); pk.w = pk2(f1.z, f1.w);
    }
    int byte = (row*256 + seg*16) ^ ((row & 7) << 4);
    *(uint4*)(smem + byte) = pk;
  }
  __syncthreads();

  int w = t >> 6, l = t & 63;

  bf16x8 bfr[4][4];
  #pragma unroll
  for (int nt = 0; nt < 4; ++nt){
    int col = w*64 + nt*16 + (l & 15);
    #pragma unroll
    for (int ks = 0; ks < 4; ++ks)
      bfr[nt][ks] = *(const bf16x8*)(Wt + (size_t)col*IN_DIM + ks*32 + ((l >> 4) << 3));
  }
  float attS[4], attD[4];
  #pragma unroll
  for (int nt = 0; nt < 4; ++nt){
    attS[nt] = att_s[w*64 + nt*16 + (l & 15)];
    attD[nt] = att_d[w*64 + nt*16 + (l & 15)];
  }

  #pragma unroll
  for (int sub = 0; sub < 4; ++sub){
    bf16x8 afr[4];
    #pragma unroll
    for (int ks = 0; ks < 4; ++ks){
      int row = sub*16 + (l & 15);
      int byte = (row*256 + ks*64 + ((l >> 4) << 4)) ^ ((row & 7) << 4);
      afr[ks] = *(const bf16x8*)(smem + byte);
    }
    f32x4 acc[4] = {{0,0,0,0},{0,0,0,0},{0,0,0,0},{0,0,0,0}};
    #pragma unroll
    for (int nt = 0; nt < 4; ++nt)
      #pragma unroll
      for (int ks = 0; ks < 4; ++ks)
        acc[nt] = __builtin_amdgcn_mfma_f32_16x16x32_bf16(afr[ks], bfr[nt][ks], acc[nt], 0, 0, 0);

    #pragma unroll
    for (int r = 0; r < 4; ++r){
      float ps = 0.f, pd = 0.f;
      #pragma unroll
      for (int nt = 0; nt < 4; ++nt){
        ps = fmaf(acc[nt][r], attS[nt], ps);
        pd = fmaf(acc[nt][r], attD[nt], pd);
      }
      #pragma unroll
      for (int o = 8; o; o >>= 1){ ps += __shfl_xor(ps, o); pd += __shfl_xor(pd, o); }
      int node = nb + sub*16 + (l >> 4)*4 + r;
      if ((l & 15) == 0 && node < N){
        a_src[node*4 + w] = ps;
        a_dst[node*4 + w] = pd;
      }
    }

    #pragma unroll
    for (int nt = 0; nt < 4; ++nt){
      int ch = nt*16 + (l & 15);
      #pragma unroll
      for (int r = 0; r < 4; ++r){
        int row = sub*16 + (l >> 4)*4 + r;
        sxl[row*HC + ch*4 + w] = __half_as_ushort(__float2half(acc[nt][r]));
      }
    }
  }
  __syncthreads();
  const uint4* s4 = (const uint4*)sxl;
  uint4* g4 = (uint4*)(xl_t + (size_t)nb*HC);
  for (int c = t; c < 2048; c += 256){
    int row = c >> 5;
    if (nb + row < N) g4[c] = s4[c];
  }
}

// ---- binscatter body: partition edges into bin segments ----
// tmp word = src | (dst&255)<<20  (requires N < 2^20).
__device__ __forceinline__ void scat_body(int bid, char* smem,
    const int* ei, int* bincur, unsigned* tmp, int E, int nbins)
{
  int* h    = (int*)smem;           // 2KB
  int* base = (int*)(smem + 2048);  // 2KB
  bool i32 = detect32(ei);
  int tile0 = bid * (256*SCAT_TPE);
  for (int i = threadIdx.x; i < nbins; i += 256) h[i] = 0;
  __syncthreads();
  unsigned pk[SCAT_TPE]; int rk[SCAT_TPE];
  #pragma unroll
  for (int k = 0; k < SCAT_TPE; ++k){
    int e = tile0 + k*256 + threadIdx.x;
    if (e < E){
      int s, d;
      if (i32){ s = ei[e]; d = ei[E + e]; }
      else {
        s = (int)((const long long*)ei)[e];
        d = (int)((const long long*)ei)[(size_t)E + e];
      }
      int b = d >> 8;
      pk[k] = (unsigned)s | ((unsigned)(d & 255) << 20);
      rk[k] = atomicAdd(&h[b], 1) | (b << 16);
    }
  }
  __syncthreads();
  for (int i = threadIdx.x; i < nbins; i += 256)
    base[i] = h[i] ? atomicAdd(&bincur[i], h[i]) : 0;
  __syncthreads();
  #pragma unroll
  for (int k = 0; k < SCAT_TPE; ++k){
    int e = tile0 + k*256 + threadIdx.x;
    if (e < E){
      int b = rk[k] >> 16, r = rk[k] & 0xFFFF;
      tmp[base[b] + r] = pk[k];
    }
  }
}

// Fused dispatch: gemm blocks [0, gemmBlocks), binscatter blocks after.
__global__ __launch_bounds__(256) void k_gemm_scat(
    const float* __restrict__ x, const unsigned short* __restrict__ Wt,
    const float* __restrict__ att_s, const float* __restrict__ att_d,
    __half* __restrict__ xl_t, float* __restrict__ a_src, float* __restrict__ a_dst,
    int N, const int* ei, int* bincur, unsigned* tmp, int E, int nbins,
    int gemmBlocks)
{
  __shared__ char smem[49152];
  int bid = (int)blockIdx.x;
  if (bid < gemmBlocks)
    gemm_body(bid, smem, x, Wt, att_s, att_d, xl_t, a_src, a_dst, N);
  else
    scat_body(bid - gemmBlocks, smem, ei, bincur, tmp, E, nbins);
}

// One block per bin: per-dst counts + scan -> rowstart, csr.
__global__ __launch_bounds__(256) void k_binsort(const unsigned* __restrict__ tmp,
    const int* __restrict__ binstart, int* rowstart, int* csr, int N){
  __shared__ int c[256], c2[256], sc[256];
  int b = blockIdx.x, tid = threadIdx.x;
  int s0 = binstart[b], s1 = binstart[b+1];
  c[tid] = 0; c2[tid] = 0;
  __syncthreads();
  for (int e = s0 + tid; e < s1; e += 256)
    atomicAdd(&c[(tmp[e] >> 20) & 255], 1);
  __syncthreads();
  int v = c[tid]; sc[tid] = v;
  __syncthreads();
  #pragma unroll
  for (int off = 1; off < 256; off <<= 1){
    int t = (tid >= off) ? sc[tid-off] : 0;
    __syncthreads();
    sc[tid] += t;
    __syncthreads();
  }
  int ex = sc[tid] - v;
  int d = b*256 + tid;
  if (d < N) rowstart[d] = s0 + ex;
  sc[tid] = ex;
  __syncthreads();
  for (int e = s0 + tid; e < s1; e += 256){
    unsigned u = tmp[e];
    int dl = (u >> 20) & 255;
    int pos = s0 + sc[dl] + atomicAdd(&c2[dl], 1);
    csr[pos] = (int)(u & 0xFFFFFu);
  }
}

// One 16-lane GROUP per destination node (4 nodes/wave, 16 nodes/block).
// Direct softmax (logits O(1), shift-invariance). Per <=16-edge chunk:
// phase A on 16 lanes (exp weights -> LDS), then PV: group gathers one full
// 512B fp16 row per edge (lane i covers 32B = 4ch x 4heads), 8 v_pk_fma_f16.
__global__ __launch_bounds__(256) void k_node(
    const int* __restrict__ rowstart, const int* __restrict__ csr,
    const float4* __restrict__ a_src4, const float4* __restrict__ a_dst4,
    const __half* __restrict__ xl_t,
    const float* __restrict__ bias, const float* __restrict__ gamma,
    const float* __restrict__ beta, float* __restrict__ out, int N)
{
  __shared__ uint2 wlds[4][4][16];
  __shared__ int   slds[4][4][16];
  int wv = threadIdx.x >> 6, ln = threadIdx.x & 63;
  int g = ln >> 4, i = ln & 15;
  int node = blockIdx.x*16 + wv*4 + g;
  bool alive = node < N;
  int nc = alive ? node : N-1;

  int start = rowstart[nc];
  int end   = alive ? rowstart[nc+1] : start;
  float4 ad  = a_dst4[nc];
  float4 asl = a_src4[nc];

  float es0 = __expf(lrelu(asl.x + ad.x));
  float es1 = __expf(lrelu(asl.y + ad.y));
  float es2 = __expf(lrelu(asl.z + ad.z));
  float es3 = __expf(lrelu(asl.w + ad.w));

  __half2 s01 = __floats2half2_rn(es0, es1);
  __half2 s23 = __floats2half2_rn(es2, es3);
  const uint4* ps = (const uint4*)((const char*)xl_t + ((size_t)nc*512 + (i << 5)));
  uint4 xa = ps[0], xb = ps[1];
  __half2 acc[8];
  acc[0] = __hmul2(s01, u2h(xa.x));
  acc[1] = __hmul2(s23, u2h(xa.y));
  acc[2] = __hmul2(s01, u2h(xa.z));
  acc[3] = __hmul2(s23, u2h(xa.w));
  acc[4] = __hmul2(s01, u2h(xb.x));
  acc[5] = __hmul2(s23, u2h(xb.y));
  acc[6] = __hmul2(s01, u2h(xb.z));
  acc[7] = __hmul2(s23, u2h(xb.w));
  float lp0 = 0.f, lp1 = 0.f, lp2 = 0.f, lp3 = 0.f;

  for (int t = start; ; t += 16){
    int rem = end - t;
    rem = rem < 0 ? 0 : (rem > 16 ? 16 : rem);
    int rmax = rem;
    rmax = max(rmax, __shfl_xor(rmax, 16));
    rmax = max(rmax, __shfl_xor(rmax, 32));
    if (rmax == 0) break;

    int sid = 0;
    float e0 = 0.f, e1 = 0.f, e2 = 0.f, e3 = 0.f;
    if (i < rem){
      sid = csr[t + i];
      float4 as4 = a_src4[sid];
      e0 = __expf(lrelu(as4.x + ad.x));
      e1 = __expf(lrelu(as4.y + ad.y));
      e2 = __expf(lrelu(as4.z + ad.z));
      e3 = __expf(lrelu(as4.w + ad.w));
      lp0 += e0; lp1 += e1; lp2 += e2; lp3 += e3;
    }
    wlds[wv][g][i] = make_uint2(h2u(__floats2half2_rn(e0, e1)),
                                h2u(__floats2half2_rn(e2, e3)));
    slds[wv][g][i] = sid;

    #pragma unroll 2
    for (int j = 0; j < rmax; ++j){
      if (j < rem){
        uint2 wpk = wlds[wv][g][j];
        int sj = slds[wv][g][j];
        __half2 w01 = u2h(wpk.x), w23 = u2h(wpk.y);
        const uint4* p = (const uint4*)((const char*)xl_t + ((size_t)sj*512 + (i << 5)));
        uint4 ya = p[0], yb = p[1];
        acc[0] = __hfma2(w01, u2h(ya.x), acc[0]);
        acc[1] = __hfma2(w23, u2h(ya.y), acc[1]);
        acc[2] = __hfma2(w01, u2h(ya.z), acc[2]);
        acc[3] = __hfma2(w23, u2h(ya.w), acc[3]);
        acc[4] = __hfma2(w01, u2h(yb.x), acc[4]);
        acc[5] = __hfma2(w23, u2h(yb.y), acc[5]);
        acc[6] = __hfma2(w01, u2h(yb.z), acc[6]);
        acc[7] = __hfma2(w23, u2h(yb.w), acc[7]);
      }
    }
  }

  __half2 lp01 = __floats2half2_rn(lp0, lp1);
  __half2 lp23 = __floats2half2_rn(lp2, lp3);
  #pragma unroll
  for (int o = 8; o; o >>= 1){
    lp01 = __hadd2(lp01, u2h(__shfl_xor(h2u(lp01), o)));
    lp23 = __hadd2(lp23, u2h(__shfl_xor(h2u(lp23), o)));
  }
  float r0 = __builtin_amdgcn_rcpf(__low2float(lp01) + es0);
  float r1 = __builtin_amdgcn_rcpf(__high2float(lp01) + es1);
  float r2 = __builtin_amdgcn_rcpf(__low2float(lp23) + es2);
  float r3 = __builtin_amdgcn_rcpf(__high2float(lp23) + es3);

  float4 b4 = *(const float4*)(bias + 4*i);
  float o0 = 0.25f*(__low2float(acc[0])*r0 + __high2float(acc[0])*r1 +
                    __low2float(acc[1])*r2 + __high2float(acc[1])*r3) + b4.x;
  float o1 = 0.25f*(__low2float(acc[2])*r0 + __high2float(acc[2])*r1 +
                    __low2float(acc[3])*r2 + __high2float(acc[3])*r3) + b4.y;
  float o2 = 0.25f*(__low2float(acc[4])*r0 + __high2float(acc[4])*r1 +
                    __low2float(acc[5])*r2 + __high2float(acc[5])*r3) + b4.z;
  float o3 = 0.25f*(__low2float(acc[6])*r0 + __high2float(acc[6])*r1 +
                    __low2float(acc[7])*r2 + __high2float(acc[7])*r3) + b4.w;

  float s  = o0 + o1 + o2 + o3;
  float sq = o0*o0 + o1*o1 + o2*o2 + o3*o3;
  #pragma unroll
  for (int o = 8; o; o >>= 1){
    s  += __shfl_xor(s, o);
    sq += __shfl_xor(sq, o);
  }
  float mu = s * (1.f/OUT_DIM);
  float var = sq * (1.f/OUT_DIM) - mu*mu;
  float rs = rsqrtf(var + LN_EPS);
  float4 g4v = *(const float4*)(gamma + 4*i);
  float4 be4 = *(const float4*)(beta + 4*i);
  if (alive){
    float4 ov;
    ov.x = (o0 - mu)*rs*g4v.x + be4.x;
    ov.y = (o1 - mu)*rs*g4v.y + be4.y;
    ov.z = (o2 - mu)*rs*g4v.z + be4.z;
    ov.w = (o3 - mu)*rs*g4v.w + be4.w;
    *(float4*)(out + (size_t)node*OUT_DIM + 4*i) = ov;
  }
}

extern "C" void kernel_launch(void* const* d_in, const int* in_sizes, int n_in,
                              void* d_out, int out_size, void* d_ws, size_t ws_size,
                              hipStream_t stream)
{
  const float* x     = (const float*)d_in[0];
  const int*   ei    = (const int*)d_in[1];
  const float* W     = (const float*)d_in[2];
  const float* att_s = (const float*)d_in[3];
  const float* att_d = (const float*)d_in[4];
  const float* bias  = (const float*)d_in[5];
  const float* gamma = (const float*)d_in[6];
  const float* beta  = (const float*)d_in[7];
  float* out = (float*)d_out;

  int N = in_sizes[0] / IN_DIM;
  int E = in_sizes[1] / 2;
  int nbins = (N + 255) >> 8;

  char* ws = (char*)d_ws;
  __half* xl_t = (__half*)ws;                   ws += (size_t)N*HC*sizeof(__half);
  float* a_src = (float*)ws;                    ws += (size_t)N*HEADS*sizeof(float);
  float* a_dst = (float*)ws;                    ws += (size_t)N*HEADS*sizeof(float);
  int* rowstart = (int*)ws;                     ws += ((size_t)N+1)*sizeof(int);
  int* csr      = (int*)ws;                     ws += (size_t)E*sizeof(int);
  unsigned* tmp = (unsigned*)ws;                ws += (size_t)E*sizeof(unsigned);
  int* partials = (int*)ws;                     ws += (size_t)NHIST*MAXBINS*sizeof(int);
  int* binstart = (int*)ws;                     ws += (MAXBINS+1)*sizeof(int);
  int* bincur   = (int*)ws;                     ws += MAXBINS*sizeof(int);
  unsigned short* Wt = (unsigned short*)ws;     ws += (size_t)HC*IN_DIM*sizeof(unsigned short);

  int gemmBlocks = (N + 63)/64;
  int scatBlocks = (E + 256*SCAT_TPE - 1)/(256*SCAT_TPE);

  k_front   <<<128 + NHIST, 256, 0, stream>>>(W, Wt, ei, partials, E, nbins);
  k_binscan <<<1, 512, 0, stream>>>(partials, binstart, bincur, rowstart, nbins, N, E);
  k_gemm_scat<<<gemmBlocks + scatBlocks, 256, 0, stream>>>(
      x, Wt, att_s, att_d, xl_t, a_src, a_dst, N, ei, bincur, tmp, E, nbins,
      gemmBlocks);
  k_binsort <<<nbins, 256, 0, stream>>>(tmp, binstart, rowstart, csr, N);
  k_node    <<<(N + 15)/16, 256, 0, stream>>>(rowstart, csr,
              (const float4*)a_src, (const float4*)a_dst, xl_t,
              bias, gamma, beta, out, N);
}

// Round 10
// 221.328 us; speedup vs baseline: 1.8496x; 1.0023x over previous
//
#include <hip/hip_runtime.h>
#include <hip/hip_fp16.h>

#define IN_DIM   128
#define HC       256   // HEADS*OUT_DIM
#define OUT_DIM  64
#define HEADS    4
#define NEG_SLOPE 0.2f
#define LN_EPS   1e-5f
#define DBITS    6
#define DPB      64    // dsts per bin
#define MAXBINS  2048  // supports N <= 131072
#define CAP      2048  // LDS edge capacity per bin (mean ~1020, sigma ~32)
#define NHIST    256   // histogram blocks in k_front
#define SCAT_TPE 16    // edges per thread in binscatter (tile = 4096)

typedef short bf16x8 __attribute__((ext_vector_type(8)));
typedef float f32x4  __attribute__((ext_vector_type(4)));

__device__ __forceinline__ float lrelu(float a){ return a > 0.f ? a : NEG_SLOPE * a; }

__device__ __forceinline__ unsigned short f2bf(float f){
  unsigned u = __float_as_uint(f);
  u = u + 0x7fffu + ((u >> 16) & 1u);   // round-to-nearest-even
  return (unsigned short)(u >> 16);
}
__device__ __forceinline__ unsigned pk2(float a, float b){
  return (unsigned)f2bf(a) | ((unsigned)f2bf(b) << 16);
}
__device__ __forceinline__ __half2 u2h(unsigned u){ return *(__half2*)&u; }
__device__ __forceinline__ unsigned h2u(__half2 h){ return *(unsigned*)&h; }

// Per-wave int32/int64 layout detection: int64 node ids < 2^31 have zero odd
// 32-bit words; int32 layout would need 32 random node ids == 0 to fool this.
__device__ __forceinline__ bool detect32(const int* ei){
  int ln = threadIdx.x & 63;
  unsigned probe = (ln < 32) ? (unsigned)ei[2*ln + 1] : 0u;
  return __ballot(probe != 0) != 0ull;
}

// Fused front-end: blocks [0,128) transpose W -> Wt (bf16, MFMA B-frag
// friendly); blocks [128,128+NHIST) LDS-histogram bins, merge with one
// global atomic per (bin,block). bincnt pre-zeroed by hipMemsetAsync.
__global__ __launch_bounds__(256) void k_front(
    const float* __restrict__ W, unsigned short* __restrict__ Wt,
    const int* ei, int* __restrict__ bincnt, int E, int nbins)
{
  if (blockIdx.x < 128){
    int n = blockIdx.x*2 + (threadIdx.x >> 7);
    int k = threadIdx.x & 127;
    Wt[n*IN_DIM + k] = f2bf(W[k*HC + n]);
    return;
  }
  __shared__ int h[MAXBINS];
  bool i32 = detect32(ei);
  for (int i = threadIdx.x; i < nbins; i += 256) h[i] = 0;
  __syncthreads();
  int slot = blockIdx.x - 128;
  if (i32){
    const int* dstp = ei + E;
    for (int e = slot*256 + threadIdx.x; e < E; e += NHIST*256)
      atomicAdd(&h[dstp[e] >> DBITS], 1);
  } else {
    const long long* dstp = (const long long*)ei + E;
    for (int e = slot*256 + threadIdx.x; e < E; e += NHIST*256)
      atomicAdd(&h[((int)dstp[e]) >> DBITS], 1);
  }
  __syncthreads();
  for (int i = threadIdx.x; i < nbins; i += 256)
    if (h[i]) atomicAdd(&bincnt[i], h[i]);
}

// Single block, 1024 threads, 2 bins/thread: exclusive scan of bin counts.
__global__ __launch_bounds__(1024) void k_binscan(const int* __restrict__ bincnt,
    int* binstart, int* bincur, int nbins, int E)
{
  __shared__ int sh[1024];
  int t = threadIdx.x;
  int i0 = 2*t, i1 = 2*t + 1;
  int a = (i0 < nbins) ? bincnt[i0] : 0;
  int b = (i1 < nbins) ? bincnt[i1] : 0;
  int s = a + b;
  sh[t] = s; __syncthreads();
  #pragma unroll
  for (int off = 1; off < 1024; off <<= 1){
    int v = (t >= off) ? sh[t-off] : 0;
    __syncthreads();
    sh[t] += v;
    __syncthreads();
  }
  int ex = sh[t] - s;
  if (i0 < nbins){ binstart[i0] = ex;     bincur[i0] = ex; }
  if (i1 < nbins){ binstart[i1] = ex + a; bincur[i1] = ex + a; }
  if (t == 0) binstart[nbins] = E;
}

// ---- GEMM body (MFMA): xl_t = fp16(x@W) head-interleaved + logits ----
// LDS: sxa 16KB (x tile, XOR-swizzled) + sxl 8KB (per-sub output staging).
__device__ __forceinline__ void gemm_body(int bid, char* smem,
    const float* __restrict__ x, const unsigned short* __restrict__ Wt,
    const float* __restrict__ att_s, const float* __restrict__ att_d,
    __half* __restrict__ xl_t, float* __restrict__ a_src,
    float* __restrict__ a_dst, int N)
{
  unsigned short* sxl = (unsigned short*)(smem + 16384);  // 8KB per-sub staging
  int t = threadIdx.x;
  int nb = bid * 64;

  #pragma unroll
  for (int it = 0; it < 4; ++it){
    int idx = it*256 + t;
    int row = idx >> 4, seg = idx & 15;
    uint4 pk = make_uint4(0,0,0,0);
    if (nb + row < N){
      const float* xr = x + (size_t)(nb + row)*IN_DIM + seg*8;
      float4 f0 = *(const float4*)xr;
      float4 f1 = *(const float4*)(xr + 4);
      pk.x = pk2(f0.x, f0.y); pk.y = pk2(f0.z, f0.w);
      pk.z = pk2(f1.x, f1.y); pk.w = pk2(f1.z, f1.w);
    }
    int byte = (row*256 + seg*16) ^ ((row & 7) << 4);
    *(uint4*)(smem + byte) = pk;
  }
  __syncthreads();

  int w = t >> 6, l = t & 63;

  bf16x8 bfr[4][4];
  #pragma unroll
  for (int nt = 0; nt < 4; ++nt){
    int col = w*64 + nt*16 + (l & 15);
    #pragma unroll
    for (int ks = 0; ks < 4; ++ks)
      bfr[nt][ks] = *(const bf16x8*)(Wt + (size_t)col*IN_DIM + ks*32 + ((l >> 4) << 3));
  }
  float attS[4], attD[4];
  #pragma unroll
  for (int nt = 0; nt < 4; ++nt){
    attS[nt] = att_s[w*64 + nt*16 + (l & 15)];
    attD[nt] = att_d[w*64 + nt*16 + (l & 15)];
  }

  #pragma unroll
  for (int sub = 0; sub < 4; ++sub){
    bf16x8 afr[4];
    #pragma unroll
    for (int ks = 0; ks < 4; ++ks){
      int row = sub*16 + (l & 15);
      int byte = (row*256 + ks*64 + ((l >> 4) << 4)) ^ ((row & 7) << 4);
      afr[ks] = *(const bf16x8*)(smem + byte);
    }
    f32x4 acc[4] = {{0,0,0,0},{0,0,0,0},{0,0,0,0},{0,0,0,0}};
    #pragma unroll
    for (int nt = 0; nt < 4; ++nt)
      #pragma unroll
      for (int ks = 0; ks < 4; ++ks)
        acc[nt] = __builtin_amdgcn_mfma_f32_16x16x32_bf16(afr[ks], bfr[nt][ks], acc[nt], 0, 0, 0);

    #pragma unroll
    for (int r = 0; r < 4; ++r){
      float ps = 0.f, pd = 0.f;
      #pragma unroll
      for (int nt = 0; nt < 4; ++nt){
        ps = fmaf(acc[nt][r], attS[nt], ps);
        pd = fmaf(acc[nt][r], attD[nt], pd);
      }
      #pragma unroll
      for (int o = 8; o; o >>= 1){ ps += __shfl_xor(ps, o); pd += __shfl_xor(pd, o); }
      int node = nb + sub*16 + (l >> 4)*4 + r;
      if ((l & 15) == 0 && node < N){
        a_src[node*4 + w] = ps;
        a_dst[node*4 + w] = pd;
      }
    }

    // stage this sub's 16 rows (8KB) and copy out
    #pragma unroll
    for (int nt = 0; nt < 4; ++nt){
      int ch = nt*16 + (l & 15);
      #pragma unroll
      for (int r = 0; r < 4; ++r){
        int row = (l >> 4)*4 + r;
        sxl[row*HC + ch*4 + w] = __half_as_ushort(__float2half(acc[nt][r]));
      }
    }
    __syncthreads();
    const uint4* s4 = (const uint4*)sxl;
    uint4* g4 = (uint4*)(xl_t + (size_t)(nb + sub*16)*HC);
    #pragma unroll
    for (int c = t; c < 512; c += 256){
      int row = c >> 5;
      if (nb + sub*16 + row < N) g4[c] = s4[c];
    }
    __syncthreads();
  }
}

// ---- binscatter body: partition edges into bin segments ----
// tmp word = src | (dst & 63) << 20  (requires N < 2^20).
__device__ __forceinline__ void scat_body(int bid, char* smem,
    const int* ei, int* bincur, unsigned* tmp, int E, int nbins)
{
  int* h    = (int*)smem;                    // up to 8KB
  int* base = (int*)(smem + MAXBINS*4);      // up to 8KB
  bool i32 = detect32(ei);
  int tile0 = bid * (256*SCAT_TPE);
  for (int i = threadIdx.x; i < nbins; i += 256) h[i] = 0;
  __syncthreads();
  unsigned pk[SCAT_TPE]; int rk[SCAT_TPE];
  #pragma unroll
  for (int k = 0; k < SCAT_TPE; ++k){
    int e = tile0 + k*256 + threadIdx.x;
    if (e < E){
      int s, d;
      if (i32){ s = ei[e]; d = ei[E + e]; }
      else {
        s = (int)((const long long*)ei)[e];
        d = (int)((const long long*)ei)[(size_t)E + e];
      }
      int b = d >> DBITS;
      pk[k] = (unsigned)s | ((unsigned)(d & (DPB-1)) << 20);
      rk[k] = atomicAdd(&h[b], 1) | (b << 16);
    }
  }
  __syncthreads();
  for (int i = threadIdx.x; i < nbins; i += 256)
    base[i] = h[i] ? atomicAdd(&bincur[i], h[i]) : 0;
  __syncthreads();
  #pragma unroll
  for (int k = 0; k < SCAT_TPE; ++k){
    int e = tile0 + k*256 + threadIdx.x;
    if (e < E){
      int b = rk[k] >> 16, r = rk[k] & 0xFFFF;
      tmp[base[b] + r] = pk[k];
    }
  }
}

// Fused dispatch: gemm blocks [0, gemmBlocks), binscatter blocks after.
__global__ __launch_bounds__(256) void k_gemm_scat(
    const float* __restrict__ x, const unsigned short* __restrict__ Wt,
    const float* __restrict__ att_s, const float* __restrict__ att_d,
    __half* __restrict__ xl_t, float* __restrict__ a_src, float* __restrict__ a_dst,
    int N, const int* ei, int* bincur, unsigned* tmp, int E, int nbins,
    int gemmBlocks)
{
  __shared__ char smem[24576];
  int bid = (int)blockIdx.x;
  if (bid < gemmBlocks)
    gemm_body(bid, smem, x, Wt, att_s, att_d, xl_t, a_src, a_dst, N);
  else
    scat_body(bid - gemmBlocks, smem, ei, bincur, tmp, E, nbins);
}

// One block per bin (64 dsts): in-LDS binsort (count -> scan -> rank-scatter)
// of the bin's tmp segment, then 16-lane groups process 4 nodes each with
// direct-softmax attention (logits O(1); shift-invariance) + head-avg + LN.
// PV: group gathers one 512B fp16 row per edge (lane i covers 32B = 4ch x
// 4heads), 8 v_pk_fma_f16 per edge per lane-quarter.
__global__ __launch_bounds__(256) void k_node(
    const int* __restrict__ binstart, const unsigned* __restrict__ tmp,
    int* __restrict__ csr,
    const float4* __restrict__ a_src4, const float4* __restrict__ a_dst4,
    const __half* __restrict__ xl_t,
    const float* __restrict__ bias, const float* __restrict__ gamma,
    const float* __restrict__ beta, float* __restrict__ out, int N)
{
  __shared__ int cnt[DPB], sc[DPB], cur[DPB];
  __shared__ int lcsr[CAP];
  __shared__ uint2 wlds[16][16];
  int b = blockIdx.x, tid = threadIdx.x;
  int s0 = binstart[b], s1 = binstart[b+1];
  int seg = s1 - s0;

  if (tid < DPB) cnt[tid] = 0;
  __syncthreads();
  for (int e = s0 + tid; e < s1; e += 256)
    atomicAdd(&cnt[(tmp[e] >> 20) & (DPB-1)], 1);
  __syncthreads();
  if (tid < DPB) sc[tid] = cnt[tid];
  __syncthreads();
  #pragma unroll
  for (int off = 1; off < DPB; off <<= 1){
    int v = (tid < DPB && tid >= off) ? sc[tid-off] : 0;
    __syncthreads();
    if (tid < DPB) sc[tid] += v;
    __syncthreads();
  }
  if (tid < DPB){ int ex = sc[tid] - cnt[tid]; sc[tid] = ex; cur[tid] = ex; }
  __syncthreads();

  // rank-scatter into LDS (global csr fallback for pathological bins)
  int* ebuf = (seg <= CAP) ? lcsr : (csr + s0);
  for (int e = s0 + tid; e < s1; e += 256){
    unsigned u = tmp[e];
    int dl = (u >> 20) & (DPB-1);
    int r = atomicAdd(&cur[dl], 1);
    ebuf[r] = (int)(u & 0xFFFFFu);
  }
  __syncthreads();

  int gg = tid >> 4, i = tid & 15;
  for (int n = 0; n < 4; ++n){
    int dl = gg*4 + n;
    int node = b*DPB + dl;
    if (node >= N) continue;
    int lstart = sc[dl], lend = lstart + cnt[dl];

    float4 ad  = a_dst4[node];
    float4 asl = a_src4[node];
    float es0 = __expf(lrelu(asl.x + ad.x));
    float es1 = __expf(lrelu(asl.y + ad.y));
    float es2 = __expf(lrelu(asl.z + ad.z));
    float es3 = __expf(lrelu(asl.w + ad.w));

    __half2 s01 = __floats2half2_rn(es0, es1);
    __half2 s23 = __floats2half2_rn(es2, es3);
    const uint4* ps = (const uint4*)((const char*)xl_t + ((size_t)node*512 + (i << 5)));
    uint4 xa = ps[0], xb = ps[1];
    __half2 acc[8];
    acc[0] = __hmul2(s01, u2h(xa.x));
    acc[1] = __hmul2(s23, u2h(xa.y));
    acc[2] = __hmul2(s01, u2h(xa.z));
    acc[3] = __hmul2(s23, u2h(xa.w));
    acc[4] = __hmul2(s01, u2h(xb.x));
    acc[5] = __hmul2(s23, u2h(xb.y));
    acc[6] = __hmul2(s01, u2h(xb.z));
    acc[7] = __hmul2(s23, u2h(xb.w));
    float lp0 = 0.f, lp1 = 0.f, lp2 = 0.f, lp3 = 0.f;

    for (int t2 = lstart; t2 < lend; t2 += 16){
      int rem = lend - t2; if (rem > 16) rem = 16;
      float e0 = 0.f, e1 = 0.f, e2 = 0.f, e3 = 0.f;
      if (i < rem){
        int sid = ebuf[t2 + i];
        float4 as4 = a_src4[sid];
        e0 = __expf(lrelu(as4.x + ad.x));
        e1 = __expf(lrelu(as4.y + ad.y));
        e2 = __expf(lrelu(as4.z + ad.z));
        e3 = __expf(lrelu(as4.w + ad.w));
        lp0 += e0; lp1 += e1; lp2 += e2; lp3 += e3;
      }
      wlds[gg][i] = make_uint2(h2u(__floats2half2_rn(e0, e1)),
                               h2u(__floats2half2_rn(e2, e3)));

      #pragma unroll 2
      for (int j = 0; j < rem; ++j){
        uint2 wpk = wlds[gg][j];
        int sj = ebuf[t2 + j];
        __half2 w01 = u2h(wpk.x), w23 = u2h(wpk.y);
        const uint4* p = (const uint4*)((const char*)xl_t + ((size_t)sj*512 + (i << 5)));
        uint4 ya = p[0], yb = p[1];
        acc[0] = __hfma2(w01, u2h(ya.x), acc[0]);
        acc[1] = __hfma2(w23, u2h(ya.y), acc[1]);
        acc[2] = __hfma2(w01, u2h(ya.z), acc[2]);
        acc[3] = __hfma2(w23, u2h(ya.w), acc[3]);
        acc[4] = __hfma2(w01, u2h(yb.x), acc[4]);
        acc[5] = __hfma2(w23, u2h(yb.y), acc[5]);
        acc[6] = __hfma2(w01, u2h(yb.z), acc[6]);
        acc[7] = __hfma2(w23, u2h(yb.w), acc[7]);
      }
    }

    // denominators: packed reduce within the 16-lane group
    __half2 lp01 = __floats2half2_rn(lp0, lp1);
    __half2 lp23 = __floats2half2_rn(lp2, lp3);
    #pragma unroll
    for (int o = 8; o; o >>= 1){
      lp01 = __hadd2(lp01, u2h(__shfl_xor(h2u(lp01), o)));
      lp23 = __hadd2(lp23, u2h(__shfl_xor(h2u(lp23), o)));
    }
    float r0 = __builtin_amdgcn_rcpf(__low2float(lp01) + es0);
    float r1 = __builtin_amdgcn_rcpf(__high2float(lp01) + es1);
    float r2 = __builtin_amdgcn_rcpf(__low2float(lp23) + es2);
    float r3 = __builtin_amdgcn_rcpf(__high2float(lp23) + es3);

    float4 b4 = *(const float4*)(bias + 4*i);
    float o0 = 0.25f*(__low2float(acc[0])*r0 + __high2float(acc[0])*r1 +
                      __low2float(acc[1])*r2 + __high2float(acc[1])*r3) + b4.x;
    float o1 = 0.25f*(__low2float(acc[2])*r0 + __high2float(acc[2])*r1 +
                      __low2float(acc[3])*r2 + __high2float(acc[3])*r3) + b4.y;
    float o2 = 0.25f*(__low2float(acc[4])*r0 + __high2float(acc[4])*r1 +
                      __low2float(acc[5])*r2 + __high2float(acc[5])*r3) + b4.z;
    float o3 = 0.25f*(__low2float(acc[6])*r0 + __high2float(acc[6])*r1 +
                      __low2float(acc[7])*r2 + __high2float(acc[7])*r3) + b4.w;

    float s  = o0 + o1 + o2 + o3;
    float sq = o0*o0 + o1*o1 + o2*o2 + o3*o3;
    #pragma unroll
    for (int o = 8; o; o >>= 1){
      s  += __shfl_xor(s, o);
      sq += __shfl_xor(sq, o);
    }
    float mu = s * (1.f/OUT_DIM);
    float var = sq * (1.f/OUT_DIM) - mu*mu;
    float rs = rsqrtf(var + LN_EPS);
    float4 g4v = *(const float4*)(gamma + 4*i);
    float4 be4 = *(const float4*)(beta + 4*i);
    float4 ov;
    ov.x = (o0 - mu)*rs*g4v.x + be4.x;
    ov.y = (o1 - mu)*rs*g4v.y + be4.y;
    ov.z = (o2 - mu)*rs*g4v.z + be4.z;
    ov.w = (o3 - mu)*rs*g4v.w + be4.w;
    *(float4*)(out + (size_t)node*OUT_DIM + 4*i) = ov;
  }
}

extern "C" void kernel_launch(void* const* d_in, const int* in_sizes, int n_in,
                              void* d_out, int out_size, void* d_ws, size_t ws_size,
                              hipStream_t stream)
{
  const float* x     = (const float*)d_in[0];
  const int*   ei    = (const int*)d_in[1];
  const float* W     = (const float*)d_in[2];
  const float* att_s = (const float*)d_in[3];
  const float* att_d = (const float*)d_in[4];
  const float* bias  = (const float*)d_in[5];
  const float* gamma = (const float*)d_in[6];
  const float* beta  = (const float*)d_in[7];
  float* out = (float*)d_out;

  int N = in_sizes[0] / IN_DIM;
  int E = in_sizes[1] / 2;
  int nbins = (N + DPB - 1) >> DBITS;

  char* ws = (char*)d_ws;
  __half* xl_t = (__half*)ws;                   ws += (size_t)N*HC*sizeof(__half);
  float* a_src = (float*)ws;                    ws += (size_t)N*HEADS*sizeof(float);
  float* a_dst = (float*)ws;                    ws += (size_t)N*HEADS*sizeof(float);
  int* csr      = (int*)ws;                     ws += (size_t)E*sizeof(int);
  unsigned* tmp = (unsigned*)ws;                ws += (size_t)E*sizeof(unsigned);
  int* bincnt   = (int*)ws;                     ws += MAXBINS*sizeof(int);
  int* binstart = (int*)ws;                     ws += (MAXBINS+1)*sizeof(int);
  int* bincur   = (int*)ws;                     ws += MAXBINS*sizeof(int);
  unsigned short* Wt = (unsigned short*)ws;     ws += (size_t)HC*IN_DIM*sizeof(unsigned short);

  int gemmBlocks = (N + 63)/64;
  int scatBlocks = (E + 256*SCAT_TPE - 1)/(256*SCAT_TPE);

  hipMemsetAsync(bincnt, 0, (size_t)nbins*sizeof(int), stream);
  k_front   <<<128 + NHIST, 256, 0, stream>>>(W, Wt, ei, bincnt, E, nbins);
  k_binscan <<<1, 1024, 0, stream>>>(bincnt, binstart, bincur, nbins, E);
  k_gemm_scat<<<gemmBlocks + scatBlocks, 256, 0, stream>>>(
      x, Wt, att_s, att_d, xl_t, a_src, a_dst, N, ei, bincur, tmp, E, nbins,
      gemmBlocks);
  k_node    <<<nbins, 256, 0, stream>>>(binstart, tmp, csr,
              (const float4*)a_src, (const float4*)a_dst, xl_t,
              bias, gamma, beta, out, N);
}

// Round 11
// 218.674 us; speedup vs baseline: 1.8720x; 1.0121x over previous
//
#include <hip/hip_runtime.h>
#include <hip/hip_fp16.h>

#define IN_DIM   128
#define HC       256   // HEADS*OUT_DIM
#define OUT_DIM  64
#define HEADS    4
#define NEG_SLOPE 0.2f
#define LN_EPS   1e-5f
#define DBITS    5
#define DPB      32    // dsts per bin
#define MAXBINS  4096  // supports N <= 131072
#define CAP      768   // LDS edge capacity per bin (mean ~512, sigma ~23)
#define NHIST    256   // histogram blocks in k_front
#define SCAT_TPE 16    // edges per thread in binscatter (tile = 4096)

typedef short bf16x8 __attribute__((ext_vector_type(8)));
typedef float f32x4  __attribute__((ext_vector_type(4)));

__device__ __forceinline__ float lrelu(float a){ return a > 0.f ? a : NEG_SLOPE * a; }

__device__ __forceinline__ unsigned short f2bf(float f){
  unsigned u = __float_as_uint(f);
  u = u + 0x7fffu + ((u >> 16) & 1u);   // round-to-nearest-even
  return (unsigned short)(u >> 16);
}
__device__ __forceinline__ unsigned pk2(float a, float b){
  return (unsigned)f2bf(a) | ((unsigned)f2bf(b) << 16);
}
__device__ __forceinline__ __half2 u2h(unsigned u){ return *(__half2*)&u; }
__device__ __forceinline__ unsigned h2u(__half2 h){ return *(unsigned*)&h; }

// Per-wave int32/int64 layout detection: int64 node ids < 2^31 have zero odd
// 32-bit words; int32 layout would need 32 random node ids == 0 to fool this.
__device__ __forceinline__ bool detect32(const int* ei){
  int ln = threadIdx.x & 63;
  unsigned probe = (ln < 32) ? (unsigned)ei[2*ln + 1] : 0u;
  return __ballot(probe != 0) != 0ull;
}

// Fused front-end: blocks [0,128) transpose W -> Wt; blocks [128,128+NHIST)
// LDS-histogram bins, merged with one global atomic per (bin,block).
// bincnt pre-zeroed by hipMemsetAsync.
__global__ __launch_bounds__(256) void k_front(
    const float* __restrict__ W, unsigned short* __restrict__ Wt,
    const int* ei, int* __restrict__ bincnt, int E, int nbins)
{
  if (blockIdx.x < 128){
    int n = blockIdx.x*2 + (threadIdx.x >> 7);
    int k = threadIdx.x & 127;
    Wt[n*IN_DIM + k] = f2bf(W[k*HC + n]);
    return;
  }
  __shared__ int h[MAXBINS];
  bool i32 = detect32(ei);
  for (int i = threadIdx.x; i < nbins; i += 256) h[i] = 0;
  __syncthreads();
  int slot = blockIdx.x - 128;
  if (i32){
    const int* dstp = ei + E;
    for (int e = slot*256 + threadIdx.x; e < E; e += NHIST*256)
      atomicAdd(&h[dstp[e] >> DBITS], 1);
  } else {
    const long long* dstp = (const long long*)ei + E;
    for (int e = slot*256 + threadIdx.x; e < E; e += NHIST*256)
      atomicAdd(&h[((int)dstp[e]) >> DBITS], 1);
  }
  __syncthreads();
  for (int i = threadIdx.x; i < nbins; i += 256)
    if (h[i]) atomicAdd(&bincnt[i], h[i]);
}

// Single block, 1024 threads, 4 bins/thread: exclusive scan of bin counts.
__global__ __launch_bounds__(1024) void k_binscan(const int* __restrict__ bincnt,
    int* binstart, int* bincur, int nbins, int E)
{
  __shared__ int sh[1024];
  int t = threadIdx.x;
  int v[4]; int s = 0;
  #pragma unroll
  for (int k = 0; k < 4; ++k){
    int i = 4*t + k;
    v[k] = (i < nbins) ? bincnt[i] : 0;
    s += v[k];
  }
  sh[t] = s; __syncthreads();
  #pragma unroll
  for (int off = 1; off < 1024; off <<= 1){
    int u = (t >= off) ? sh[t-off] : 0;
    __syncthreads();
    sh[t] += u;
    __syncthreads();
  }
  int run = sh[t] - s;
  #pragma unroll
  for (int k = 0; k < 4; ++k){
    int i = 4*t + k;
    if (i < nbins){ binstart[i] = run; bincur[i] = run; }
    run += v[k];
  }
  if (t == 0) binstart[nbins] = E;
}

// ---- GEMM body (MFMA): xl_t = fp16(x@W) head-interleaved + logits ----
// LDS: sxa 16KB (x tile, XOR-swizzled) + sxl 8KB (per-sub output staging).
__device__ __forceinline__ void gemm_body(int bid, char* smem,
    const float* __restrict__ x, const unsigned short* __restrict__ Wt,
    const float* __restrict__ att_s, const float* __restrict__ att_d,
    __half* __restrict__ xl_t, float* __restrict__ a_src,
    float* __restrict__ a_dst, int N)
{
  unsigned short* sxl = (unsigned short*)(smem + 16384);  // 8KB per-sub staging
  int t = threadIdx.x;
  int nb = bid * 64;

  #pragma unroll
  for (int it = 0; it < 4; ++it){
    int idx = it*256 + t;
    int row = idx >> 4, seg = idx & 15;
    uint4 pk = make_uint4(0,0,0,0);
    if (nb + row < N){
      const float* xr = x + (size_t)(nb + row)*IN_DIM + seg*8;
      float4 f0 = *(const float4*)xr;
      float4 f1 = *(const float4*)(xr + 4);
      pk.x = pk2(f0.x, f0.y); pk.y = pk2(f0.z, f0.w);
      pk.z = pk2(f1.x, f1.y); pk.w = pk2(f1.z, f1.w);
    }
    int byte = (row*256 + seg*16) ^ ((row & 7) << 4);
    *(uint4*)(smem + byte) = pk;
  }
  __syncthreads();

  int w = t >> 6, l = t & 63;

  bf16x8 bfr[4][4];
  #pragma unroll
  for (int nt = 0; nt < 4; ++nt){
    int col = w*64 + nt*16 + (l & 15);
    #pragma unroll
    for (int ks = 0; ks < 4; ++ks)
      bfr[nt][ks] = *(const bf16x8*)(Wt + (size_t)col*IN_DIM + ks*32 + ((l >> 4) << 3));
  }
  float attS[4], attD[4];
  #pragma unroll
  for (int nt = 0; nt < 4; ++nt){
    attS[nt] = att_s[w*64 + nt*16 + (l & 15)];
    attD[nt] = att_d[w*64 + nt*16 + (l & 15)];
  }

  #pragma unroll
  for (int sub = 0; sub < 4; ++sub){
    bf16x8 afr[4];
    #pragma unroll
    for (int ks = 0; ks < 4; ++ks){
      int row = sub*16 + (l & 15);
      int byte = (row*256 + ks*64 + ((l >> 4) << 4)) ^ ((row & 7) << 4);
      afr[ks] = *(const bf16x8*)(smem + byte);
    }
    f32x4 acc[4] = {{0,0,0,0},{0,0,0,0},{0,0,0,0},{0,0,0,0}};
    #pragma unroll
    for (int nt = 0; nt < 4; ++nt)
      #pragma unroll
      for (int ks = 0; ks < 4; ++ks)
        acc[nt] = __builtin_amdgcn_mfma_f32_16x16x32_bf16(afr[ks], bfr[nt][ks], acc[nt], 0, 0, 0);

    #pragma unroll
    for (int r = 0; r < 4; ++r){
      float ps = 0.f, pd = 0.f;
      #pragma unroll
      for (int nt = 0; nt < 4; ++nt){
        ps = fmaf(acc[nt][r], attS[nt], ps);
        pd = fmaf(acc[nt][r], attD[nt], pd);
      }
      #pragma unroll
      for (int o = 8; o; o >>= 1){ ps += __shfl_xor(ps, o); pd += __shfl_xor(pd, o); }
      int node = nb + sub*16 + (l >> 4)*4 + r;
      if ((l & 15) == 0 && node < N){
        a_src[node*4 + w] = ps;
        a_dst[node*4 + w] = pd;
      }
    }

    #pragma unroll
    for (int nt = 0; nt < 4; ++nt){
      int ch = nt*16 + (l & 15);
      #pragma unroll
      for (int r = 0; r < 4; ++r){
        int row = (l >> 4)*4 + r;
        sxl[row*HC + ch*4 + w] = __half_as_ushort(__float2half(acc[nt][r]));
      }
    }
    __syncthreads();
    const uint4* s4 = (const uint4*)sxl;
    uint4* g4 = (uint4*)(xl_t + (size_t)(nb + sub*16)*HC);
    #pragma unroll
    for (int c = t; c < 512; c += 256){
      int row = c >> 5;
      if (nb + sub*16 + row < N) g4[c] = s4[c];
    }
    __syncthreads();
  }
}

// ---- binscatter body: partition edges into bin segments ----
// LDS counters packed 2x16-bit per int (counts <= 4096, no carry).
// tmp word = src | (dst & 31) << 20  (requires N < 2^20).
__device__ __forceinline__ void scat_body(int bid, char* smem,
    const int* ei, int* bincur, unsigned* tmp, int E, int nbins)
{
  int* h32  = (int*)smem;                  // 8KB packed counters
  int* base = (int*)(smem + 8192);         // 16KB
  bool i32 = detect32(ei);
  int tile0 = bid * (256*SCAT_TPE);
  for (int i = threadIdx.x; i < ((nbins+1)>>1); i += 256) h32[i] = 0;
  __syncthreads();
  unsigned pk[SCAT_TPE]; int rk[SCAT_TPE];
  #pragma unroll
  for (int k = 0; k < SCAT_TPE; ++k){
    int e = tile0 + k*256 + threadIdx.x;
    if (e < E){
      int s, d;
      if (i32){ s = ei[e]; d = ei[E + e]; }
      else {
        s = (int)((const long long*)ei)[e];
        d = (int)((const long long*)ei)[(size_t)E + e];
      }
      int b = d >> DBITS;
      pk[k] = (unsigned)s | ((unsigned)(d & (DPB-1)) << 20);
      int sh = (b & 1) << 4;
      unsigned old = (unsigned)atomicAdd(&h32[b >> 1], 1 << sh);
      rk[k] = (int)((old >> sh) & 0xFFFFu) | (b << 12);
    }
  }
  __syncthreads();
  for (int i = threadIdx.x; i < nbins; i += 256){
    int c = (h32[i >> 1] >> ((i & 1) << 4)) & 0xFFFF;
    base[i] = c ? atomicAdd(&bincur[i], c) : 0;
  }
  __syncthreads();
  #pragma unroll
  for (int k = 0; k < SCAT_TPE; ++k){
    int e = tile0 + k*256 + threadIdx.x;
    if (e < E){
      int b = rk[k] >> 12, r = rk[k] & 0xFFF;
      tmp[base[b] + r] = pk[k];
    }
  }
}

// Fused dispatch: gemm blocks [0, gemmBlocks), binscatter blocks after.
__global__ __launch_bounds__(256) void k_gemm_scat(
    const float* __restrict__ x, const unsigned short* __restrict__ Wt,
    const float* __restrict__ att_s, const float* __restrict__ att_d,
    __half* __restrict__ xl_t, float* __restrict__ a_src, float* __restrict__ a_dst,
    int N, const int* ei, int* bincur, unsigned* tmp, int E, int nbins,
    int gemmBlocks)
{
  __shared__ char smem[24576];
  int bid = (int)blockIdx.x;
  if (bid < gemmBlocks)
    gemm_body(bid, smem, x, Wt, att_s, att_d, xl_t, a_src, a_dst, N);
  else
    scat_body(bid - gemmBlocks, smem, ei, bincur, tmp, E, nbins);
}

// One block per bin (32 dsts): in-LDS binsort (count -> scan -> rank-scatter),
// then 16-lane groups process 2 dsts each with direct-softmax attention
// (logits O(1); shift-invariance) + head-avg + LN. PV: group gathers one
// 512B fp16 row per edge (lane i covers 32B = 4ch x 4heads), unroll 4.
__global__ __launch_bounds__(256) void k_node(
    const int* __restrict__ binstart, const unsigned* __restrict__ tmp,
    int* __restrict__ csr,
    const float4* __restrict__ a_src4, const float4* __restrict__ a_dst4,
    const __half* __restrict__ xl_t,
    const float* __restrict__ bias, const float* __restrict__ gamma,
    const float* __restrict__ beta, float* __restrict__ out, int N)
{
  __shared__ int cnt[DPB], sc[DPB], cur[DPB];
  __shared__ int lcsr[CAP];
  __shared__ uint2 wlds[16][16];
  int b = blockIdx.x, tid = threadIdx.x;
  int s0 = binstart[b], s1 = binstart[b+1];
  int seg = s1 - s0;

  if (tid < DPB){ cnt[tid] = 0; }
  __syncthreads();
  for (int e = s0 + tid; e < s1; e += 256)
    atomicAdd(&cnt[(tmp[e] >> 20) & (DPB-1)], 1);
  __syncthreads();
  if (tid < DPB) sc[tid] = cnt[tid];
  __syncthreads();
  #pragma unroll
  for (int off = 1; off < DPB; off <<= 1){
    int v = (tid < DPB && tid >= off) ? sc[tid-off] : 0;
    __syncthreads();
    if (tid < DPB) sc[tid] += v;
    __syncthreads();
  }
  if (tid < DPB){ int ex = sc[tid] - cnt[tid]; sc[tid] = ex; cur[tid] = ex; }
  __syncthreads();

  // rank-scatter into LDS (global csr fallback for pathological bins)
  int* ebuf = (seg <= CAP) ? lcsr : (csr + s0);
  for (int e = s0 + tid; e < s1; e += 256){
    unsigned u = tmp[e];
    int dl = (u >> 20) & (DPB-1);
    int r = atomicAdd(&cur[dl], 1);
    ebuf[r] = (int)(u & 0xFFFFFu);
  }
  __syncthreads();

  int gg = tid >> 4, i = tid & 15;
  #pragma unroll
  for (int n = 0; n < 2; ++n){
    int dl = gg*2 + n;
    int node = b*DPB + dl;
    if (node >= N) continue;
    int lstart = sc[dl], lend = lstart + cnt[dl];

    float4 ad  = a_dst4[node];
    float4 asl = a_src4[node];
    float es0 = __expf(lrelu(asl.x + ad.x));
    float es1 = __expf(lrelu(asl.y + ad.y));
    float es2 = __expf(lrelu(asl.z + ad.z));
    float es3 = __expf(lrelu(asl.w + ad.w));

    __half2 s01 = __floats2half2_rn(es0, es1);
    __half2 s23 = __floats2half2_rn(es2, es3);
    const uint4* ps = (const uint4*)((const char*)xl_t + ((size_t)node*512 + (i << 5)));
    uint4 xa = ps[0], xb = ps[1];
    __half2 acc[8];
    acc[0] = __hmul2(s01, u2h(xa.x));
    acc[1] = __hmul2(s23, u2h(xa.y));
    acc[2] = __hmul2(s01, u2h(xa.z));
    acc[3] = __hmul2(s23, u2h(xa.w));
    acc[4] = __hmul2(s01, u2h(xb.x));
    acc[5] = __hmul2(s23, u2h(xb.y));
    acc[6] = __hmul2(s01, u2h(xb.z));
    acc[7] = __hmul2(s23, u2h(xb.w));
    float lp0 = 0.f, lp1 = 0.f, lp2 = 0.f, lp3 = 0.f;

    for (int t2 = lstart; t2 < lend; t2 += 16){
      int rem = lend - t2; if (rem > 16) rem = 16;
      float e0 = 0.f, e1 = 0.f, e2 = 0.f, e3 = 0.f;
      if (i < rem){
        int sid = ebuf[t2 + i];
        float4 as4 = a_src4[sid];
        e0 = __expf(lrelu(as4.x + ad.x));
        e1 = __expf(lrelu(as4.y + ad.y));
        e2 = __expf(lrelu(as4.z + ad.z));
        e3 = __expf(lrelu(as4.w + ad.w));
        lp0 += e0; lp1 += e1; lp2 += e2; lp3 += e3;
      }
      wlds[gg][i] = make_uint2(h2u(__floats2half2_rn(e0, e1)),
                               h2u(__floats2half2_rn(e2, e3)));

      #pragma unroll 4
      for (int j = 0; j < rem; ++j){
        uint2 wpk = wlds[gg][j];
        int sj = ebuf[t2 + j];
        __half2 w01 = u2h(wpk.x), w23 = u2h(wpk.y);
        const uint4* p = (const uint4*)((const char*)xl_t + ((size_t)sj*512 + (i << 5)));
        uint4 ya = p[0], yb = p[1];
        acc[0] = __hfma2(w01, u2h(ya.x), acc[0]);
        acc[1] = __hfma2(w23, u2h(ya.y), acc[1]);
        acc[2] = __hfma2(w01, u2h(ya.z), acc[2]);
        acc[3] = __hfma2(w23, u2h(ya.w), acc[3]);
        acc[4] = __hfma2(w01, u2h(yb.x), acc[4]);
        acc[5] = __hfma2(w23, u2h(yb.y), acc[5]);
        acc[6] = __hfma2(w01, u2h(yb.z), acc[6]);
        acc[7] = __hfma2(w23, u2h(yb.w), acc[7]);
      }
    }

    __half2 lp01 = __floats2half2_rn(lp0, lp1);
    __half2 lp23 = __floats2half2_rn(lp2, lp3);
    #pragma unroll
    for (int o = 8; o; o >>= 1){
      lp01 = __hadd2(lp01, u2h(__shfl_xor(h2u(lp01), o)));
      lp23 = __hadd2(lp23, u2h(__shfl_xor(h2u(lp23), o)));
    }
    float r0 = __builtin_amdgcn_rcpf(__low2float(lp01) + es0);
    float r1 = __builtin_amdgcn_rcpf(__high2float(lp01) + es1);
    float r2 = __builtin_amdgcn_rcpf(__low2float(lp23) + es2);
    float r3 = __builtin_amdgcn_rcpf(__high2float(lp23) + es3);

    float4 b4 = *(const float4*)(bias + 4*i);
    float o0 = 0.25f*(__low2float(acc[0])*r0 + __high2float(acc[0])*r1 +
                      __low2float(acc[1])*r2 + __high2float(acc[1])*r3) + b4.x;
    float o1 = 0.25f*(__low2float(acc[2])*r0 + __high2float(acc[2])*r1 +
                      __low2float(acc[3])*r2 + __high2float(acc[3])*r3) + b4.y;
    float o2 = 0.25f*(__low2float(acc[4])*r0 + __high2float(acc[4])*r1 +
                      __low2float(acc[5])*r2 + __high2float(acc[5])*r3) + b4.z;
    float o3 = 0.25f*(__low2float(acc[6])*r0 + __high2float(acc[6])*r1 +
                      __low2float(acc[7])*r2 + __high2float(acc[7])*r3) + b4.w;

    float s  = o0 + o1 + o2 + o3;
    float sq = o0*o0 + o1*o1 + o2*o2 + o3*o3;
    #pragma unroll
    for (int o = 8; o; o >>= 1){
      s  += __shfl_xor(s, o);
      sq += __shfl_xor(sq, o);
    }
    float mu = s * (1.f/OUT_DIM);
    float var = sq * (1.f/OUT_DIM) - mu*mu;
    float rs = rsqrtf(var + LN_EPS);
    float4 g4v = *(const float4*)(gamma + 4*i);
    float4 be4 = *(const float4*)(beta + 4*i);
    float4 ov;
    ov.x = (o0 - mu)*rs*g4v.x + be4.x;
    ov.y = (o1 - mu)*rs*g4v.y + be4.y;
    ov.z = (o2 - mu)*rs*g4v.z + be4.z;
    ov.w = (o3 - mu)*rs*g4v.w + be4.w;
    *(float4*)(out + (size_t)node*OUT_DIM + 4*i) = ov;
  }
}

extern "C" void kernel_launch(void* const* d_in, const int* in_sizes, int n_in,
                              void* d_out, int out_size, void* d_ws, size_t ws_size,
                              hipStream_t stream)
{
  const float* x     = (const float*)d_in[0];
  const int*   ei    = (const int*)d_in[1];
  const float* W     = (const float*)d_in[2];
  const float* att_s = (const float*)d_in[3];
  const float* att_d = (const float*)d_in[4];
  const float* bias  = (const float*)d_in[5];
  const float* gamma = (const float*)d_in[6];
  const float* beta  = (const float*)d_in[7];
  float* out = (float*)d_out;

  int N = in_sizes[0] / IN_DIM;
  int E = in_sizes[1] / 2;
  int nbins = (N + DPB - 1) >> DBITS;

  char* ws = (char*)d_ws;
  __half* xl_t = (__half*)ws;                   ws += (size_t)N*HC*sizeof(__half);
  float* a_src = (float*)ws;                    ws += (size_t)N*HEADS*sizeof(float);
  float* a_dst = (float*)ws;                    ws += (size_t)N*HEADS*sizeof(float);
  int* csr      = (int*)ws;                     ws += (size_t)E*sizeof(int);
  unsigned* tmp = (unsigned*)ws;                ws += (size_t)E*sizeof(unsigned);
  int* bincnt   = (int*)ws;                     ws += MAXBINS*sizeof(int);
  int* binstart = (int*)ws;                     ws += (MAXBINS+1)*sizeof(int);
  int* bincur   = (int*)ws;                     ws += MAXBINS*sizeof(int);
  unsigned short* Wt = (unsigned short*)ws;     ws += (size_t)HC*IN_DIM*sizeof(unsigned short);

  int gemmBlocks = (N + 63)/64;
  int scatBlocks = (E + 256*SCAT_TPE - 1)/(256*SCAT_TPE);

  hipMemsetAsync(bincnt, 0, (size_t)nbins*sizeof(int), stream);
  k_front   <<<128 + NHIST, 256, 0, stream>>>(W, Wt, ei, bincnt, E, nbins);
  k_binscan <<<1, 1024, 0, stream>>>(bincnt, binstart, bincur, nbins, E);
  k_gemm_scat<<<gemmBlocks + scatBlocks, 256, 0, stream>>>(
      x, Wt, att_s, att_d, xl_t, a_src, a_dst, N, ei, bincur, tmp, E, nbins,
      gemmBlocks);
  k_node    <<<nbins, 256, 0, stream>>>(binstart, tmp, csr,
              (const float4*)a_src, (const float4*)a_dst, xl_t,
              bias, gamma, beta, out, N);
}